// Round 6
// baseline (451.704 us; speedup 1.0000x reference)
//
#include <hip/hip_runtime.h>
#include <math.h>

constexpr int Bc = 4, Tc = 1024, Ec = 1024, Hc = 16, Fc = 64;

typedef __attribute__((ext_vector_type(8))) short bf16x8;
typedef __attribute__((ext_vector_type(4))) float f32x4;

__device__ __forceinline__ ushort f2bf(float x) {
  union { float f; unsigned u; } v; v.f = x;
  unsigned r = v.u + 0x7fffu + ((v.u >> 16) & 1u);
  return (ushort)(r >> 16);
}
__device__ __forceinline__ float bf2f(ushort h) {
  union { float f; unsigned u; } v; v.u = ((unsigned)h) << 16; return v.f;
}
__device__ __forceinline__ void split3(float x, ushort& h, ushort& m, ushort& l) {
  h = f2bf(x);
  float r1 = x - bf2f(h);
  m = f2bf(r1);
  float r2 = r1 - bf2f(m);
  l = f2bf(r2);
}
__device__ __forceinline__ void split2(float x, ushort& h, ushort& l) {
  h = f2bf(x);
  l = f2bf(x - bf2f(h));
}
// Truncation split3 (~8 VALU ops): one-sided residual < 2^-22 rel.
__device__ __forceinline__ void split3t(float x, ushort& h, ushort& m, ushort& l) {
  union { float f; unsigned u; } v; v.f = x;
  h = (ushort)(v.u >> 16);
  union { float f; unsigned u; } hf; hf.u = v.u & 0xffff0000u;
  float r1 = x - hf.f;
  union { float f; unsigned u; } v1; v1.f = r1;
  m = (ushort)(v1.u >> 16);
  union { float f; unsigned u; } mf; mf.u = v1.u & 0xffff0000u;
  float r2 = r1 - mf.f;
  union { float f; unsigned u; } v2; v2.f = r2;
  l = (ushort)(v2.u >> 16);
}

// Fragment-major LDS cell: [tile][quad(0..3)][lane(0..15)][8 ushorts]
#define FRAG_IDX(tile, quad, l) (((((tile) * 4) + (quad)) * 16 + (l)) * 8)

// ---------------------------------------------------------------------------
// Merged prep: z<3 = transpose+split projection weights; z>=3 = x_split.
// One dispatch instead of two serial ones (independent work, disjoint ws).
// ---------------------------------------------------------------------------
__global__ __launch_bounds__(256) void prep_all(
    const float* __restrict__ qw, const float* __restrict__ kw,
    const float* __restrict__ vw, ushort* __restrict__ wT,
    const float* __restrict__ x, ushort* __restrict__ xh,
    ushort* __restrict__ xm, ushort* __restrict__ xl)
{
  const int zi = blockIdx.z;
  const int tid = threadIdx.x;
  if (zi >= 3) {
    // x_split: one-time split3t of x into three bf16 planes.
    const int bid = (zi - 3) * 256 + blockIdx.y * 16 + blockIdx.x;
    const int i = bid * 256 + tid;  // 8 elements per thread
    const float4 a = ((const float4*)x)[i * 2];
    const float4 b = ((const float4*)x)[i * 2 + 1];
    const float xs[8] = {a.x, a.y, a.z, a.w, b.x, b.y, b.z, b.w};
    bf16x8 h, m, l;
#pragma unroll
    for (int j = 0; j < 8; ++j) {
      ushort hu, mu, lu;
      split3t(xs[j], hu, mu, lu);
      h[j] = (short)hu; m[j] = (short)mu; l[j] = (short)lu;
    }
    ((bf16x8*)xh)[i] = h;
    ((bf16x8*)xm)[i] = m;
    ((bf16x8*)xl)[i] = l;
    return;
  }
  const float* src = (zi == 0) ? qw : (zi == 1) ? kw : vw;
  ushort* dst = wT + (size_t)(zi * 3) * (1u << 20);
  const int ns = (zi == 2) ? 1 : 3;
  const int h = blockIdx.y, e0 = blockIdx.x * 64;
  __shared__ float T[64][68];
  {
    const int er = tid >> 4, fr = (tid & 15) * 4;
#pragma unroll
    for (int i = 0; i < 4; ++i) {
      const float4 v = *(const float4*)&src[((size_t)(h * 1024 + e0 + er + i * 16)) * 64 + fr];
      *(float4*)&T[er + i * 16][fr] = v;
    }
  }
  __syncthreads();
  const int f = tid >> 2, eo = (tid & 3) * 16;
  ushort hs[16], ms[16], ls[16];
#pragma unroll
  for (int j = 0; j < 16; ++j) split3(T[eo + j][f], hs[j], ms[j], ls[j]);
  const size_t nbase = (size_t)(h * 64 + f) * 1024 + e0 + eo;
  bf16x8 v0, v1;
#pragma unroll
  for (int j = 0; j < 8; ++j) { v0[j] = (short)hs[j]; v1[j] = (short)hs[j + 8]; }
  *(bf16x8*)&dst[nbase] = v0; *(bf16x8*)&dst[nbase + 8] = v1;
  if (ns == 3) {
#pragma unroll
    for (int j = 0; j < 8; ++j) { v0[j] = (short)ms[j]; v1[j] = (short)ms[j + 8]; }
    *(bf16x8*)&dst[(1u << 20) + nbase] = v0; *(bf16x8*)&dst[(1u << 20) + nbase + 8] = v1;
#pragma unroll
    for (int j = 0; j < 8; ++j) { v0[j] = (short)ls[j]; v1[j] = (short)ls[j + 8]; }
    *(bf16x8*)&dst[(2u << 20) + nbase] = v0; *(bf16x8*)&dst[(2u << 20) + nbase + 8] = v1;
  }
}

// ---------------------------------------------------------------------------
// Pre-transpose + split2 fr weights.
// ---------------------------------------------------------------------------
__global__ __launch_bounds__(256) void transp_frw(
    const float* __restrict__ frw, ushort* __restrict__ frT)
{
  const int bb = blockIdx.z;
  const int e0 = blockIdx.x * 64, d0 = blockIdx.y * 64;
  __shared__ float T[64][68];
  const int tid = threadIdx.x;
  {
    const int er = tid >> 4, dr = (tid & 15) * 4;
#pragma unroll
    for (int i = 0; i < 4; ++i) {
      const float4 v = *(const float4*)&frw[((size_t)bb * 1024 + e0 + er + i * 16) * 1024 + d0 + dr];
      *(float4*)&T[er + i * 16][dr] = v;
    }
  }
  __syncthreads();
  const int d = tid >> 2, eo = (tid & 3) * 16;
  ushort hs[16], ls[16];
#pragma unroll
  for (int j = 0; j < 16; ++j) split2(T[eo + j][d], hs[j], ls[j]);
  const size_t nbase = ((size_t)bb * 1024 + d0 + d) * 1024 + e0 + eo;
  bf16x8 v0, v1;
#pragma unroll
  for (int j = 0; j < 8; ++j) { v0[j] = (short)hs[j]; v1[j] = (short)hs[j + 8]; }
  *(bf16x8*)&frT[nbase] = v0; *(bf16x8*)&frT[nbase + 8] = v1;
#pragma unroll
  for (int j = 0; j < 8; ++j) { v0[j] = (short)ls[j]; v1[j] = (short)ls[j + 8]; }
  *(bf16x8*)&frT[(4u << 20) + nbase] = v0; *(bf16x8*)&frT[(4u << 20) + nbase + 8] = v1;
}

// ---------------------------------------------------------------------------
// Projections from pre-split x planes. Round 6: wave-linear staging chunks
// (chunk = wave*64+lane -> fully-dense conflict-free ds_write_b128, verified
// round 2); reads via FRAG_IDX unchanged. Reg-prefetch in compute phase.
// ---------------------------------------------------------------------------
__global__ __launch_bounds__(256) void proj_all_ps(
    const ushort* __restrict__ xh, const ushort* __restrict__ xm,
    const ushort* __restrict__ xl, const ushort* __restrict__ wT,
    float* __restrict__ qf, ushort* __restrict__ kh,
    ushort* __restrict__ km, ushort* __restrict__ kl,
    ushort* __restrict__ vt)
{
  const int zi = blockIdx.z;
  const int m0 = blockIdx.x * 128, n0 = blockIdx.y * 128;
  __shared__ ushort As[3 * 4096];
  __shared__ ushort Bs[3 * 4096];
  const int tid = threadIdx.x;
  const int wave = tid >> 6, lane = tid & 63, l15 = lane & 15, quad = lane >> 4;
  const int wm = wave >> 1, wn = wave & 1;
  // wave-linear chunk mapping: chunk c1 = wave*64+lane == FRAG cell
  // (tile=wave, quad, l15); c2 = c1+256 == (tile=wave+4, quad, l15).
  const int ac1 = (wave * 64 + lane) * 8, ac2 = ac1 + 2048;
  f32x4 acc[4][4] = {};

  const size_t arow1 = (size_t)(m0 + wave * 16 + l15) * 1024 + quad * 8;
  const size_t arow2 = arow1 + (size_t)64 * 1024;
  const ushort* axh1 = xh + arow1; const ushort* axh2 = xh + arow2;
  const ushort* axm1 = xm + arow1; const ushort* axm2 = xm + arow2;
  const ushort* axl1 = xl + arow1; const ushort* axl2 = xl + arow2;

  if (zi < 2) {
    const ushort* wt = wT + (size_t)zi * 3 * (1u << 20);
    const size_t brow1 = (size_t)(n0 + wave * 16 + l15) * 1024 + quad * 8;
    const size_t brow2 = brow1 + (size_t)64 * 1024;
    // current-window fragments in registers
    bf16x8 pah0 = *(const bf16x8*)(axh1);
    bf16x8 pah1 = *(const bf16x8*)(axh2);
    bf16x8 pam0 = *(const bf16x8*)(axm1);
    bf16x8 pam1 = *(const bf16x8*)(axm2);
    bf16x8 pal0 = *(const bf16x8*)(axl1);
    bf16x8 pal1 = *(const bf16x8*)(axl2);
    bf16x8 pb0[3], pb1[3];
#pragma unroll
    for (int s = 0; s < 3; ++s) {
      const ushort* bp = wt + ((size_t)s << 20);
      pb0[s] = *(const bf16x8*)(bp + brow1);
      pb1[s] = *(const bf16x8*)(bp + brow2);
    }
    for (int k0 = 0; k0 < 1024; k0 += 32) {
      __syncthreads();
      {
        *(bf16x8*)&As[ac1] = pah0;        *(bf16x8*)&As[ac2] = pah1;
        *(bf16x8*)&As[4096 + ac1] = pam0; *(bf16x8*)&As[4096 + ac2] = pam1;
        *(bf16x8*)&As[8192 + ac1] = pal0; *(bf16x8*)&As[8192 + ac2] = pal1;
#pragma unroll
        for (int s = 0; s < 3; ++s) {
          *(bf16x8*)&Bs[s * 4096 + ac1] = pb0[s];
          *(bf16x8*)&Bs[s * 4096 + ac2] = pb1[s];
        }
      }
      __syncthreads();
      // Prefetch next window in the compute phase (latency hidden under MFMA)
      if (k0 < 992) {
        const int ko = k0 + 32;
        pah0 = *(const bf16x8*)(axh1 + ko);
        pah1 = *(const bf16x8*)(axh2 + ko);
        pam0 = *(const bf16x8*)(axm1 + ko);
        pam1 = *(const bf16x8*)(axm2 + ko);
        pal0 = *(const bf16x8*)(axl1 + ko);
        pal1 = *(const bf16x8*)(axl2 + ko);
#pragma unroll
        for (int s = 0; s < 3; ++s) {
          const ushort* bp = wt + ((size_t)s << 20) + ko;
          pb0[s] = *(const bf16x8*)(bp + brow1);
          pb1[s] = *(const bf16x8*)(bp + brow2);
        }
      }
      bf16x8 af[4][3];
#pragma unroll
      for (int tm = 0; tm < 4; ++tm)
#pragma unroll
        for (int s = 0; s < 3; ++s)
          af[tm][s] = *(const bf16x8*)&As[s * 4096 + FRAG_IDX(wm * 4 + tm, quad, l15)];
#pragma unroll
      for (int tn = 0; tn < 4; ++tn) {
        const int bi = FRAG_IDX(wn * 4 + tn, quad, l15);
        bf16x8 b0 = *(const bf16x8*)&Bs[bi];
        bf16x8 b1 = *(const bf16x8*)&Bs[4096 + bi];
        bf16x8 b2 = *(const bf16x8*)&Bs[8192 + bi];
#pragma unroll
        for (int tm = 0; tm < 4; ++tm) {
          f32x4 a = acc[tm][tn];
          a = __builtin_amdgcn_mfma_f32_16x16x32_bf16(af[tm][0], b0, a, 0, 0, 0);
          a = __builtin_amdgcn_mfma_f32_16x16x32_bf16(af[tm][0], b1, a, 0, 0, 0);
          a = __builtin_amdgcn_mfma_f32_16x16x32_bf16(af[tm][1], b0, a, 0, 0, 0);
          a = __builtin_amdgcn_mfma_f32_16x16x32_bf16(af[tm][0], b2, a, 0, 0, 0);
          a = __builtin_amdgcn_mfma_f32_16x16x32_bf16(af[tm][1], b1, a, 0, 0, 0);
          a = __builtin_amdgcn_mfma_f32_16x16x32_bf16(af[tm][2], b0, a, 0, 0, 0);
          acc[tm][tn] = a;
        }
      }
    }
#pragma unroll
    for (int tm = 0; tm < 4; ++tm) {
#pragma unroll
      for (int tn = 0; tn < 4; ++tn) {
#pragma unroll
        for (int r = 0; r < 4; ++r) {
          int m = m0 + wm * 64 + tm * 16 + quad * 4 + r;
          int n = n0 + wn * 64 + tn * 16 + l15;
          int b = m >> 10, t = m & 1023, h = n >> 6, f = n & 63;
          size_t idx = (((size_t)(b * 16 + h)) * 1024 + t) * 64 + f;
          if (zi == 0) {
            qf[idx] = acc[tm][tn][r];
          } else {
            ushort hu, mu, lu;
            split3(acc[tm][tn][r], hu, mu, lu);
            kh[idx] = hu; km[idx] = mu; kl[idx] = lu;
          }
        }
      }
    }
  } else {
    const ushort* wt = wT + (size_t)6 * (1u << 20);
    const size_t brow1 = (size_t)(n0 + wave * 16 + l15) * 1024 + quad * 8;
    const size_t brow2 = brow1 + (size_t)64 * 1024;
    bf16x8 pah0 = *(const bf16x8*)(axh1);
    bf16x8 pah1 = *(const bf16x8*)(axh2);
    bf16x8 pb0 = *(const bf16x8*)(wt + brow1);
    bf16x8 pb1 = *(const bf16x8*)(wt + brow2);
    for (int k0 = 0; k0 < 1024; k0 += 32) {
      __syncthreads();
      {
        *(bf16x8*)&As[ac1] = pah0; *(bf16x8*)&As[ac2] = pah1;
        *(bf16x8*)&Bs[ac1] = pb0;  *(bf16x8*)&Bs[ac2] = pb1;
      }
      __syncthreads();
      if (k0 < 992) {
        const int ko = k0 + 32;
        pah0 = *(const bf16x8*)(axh1 + ko);
        pah1 = *(const bf16x8*)(axh2 + ko);
        pb0 = *(const bf16x8*)(wt + brow1 + ko);
        pb1 = *(const bf16x8*)(wt + brow2 + ko);
      }
      bf16x8 af[4];
#pragma unroll
      for (int tm = 0; tm < 4; ++tm)
        af[tm] = *(const bf16x8*)&As[FRAG_IDX(wm * 4 + tm, quad, l15)];
#pragma unroll
      for (int tn = 0; tn < 4; ++tn) {
        bf16x8 b0 = *(const bf16x8*)&Bs[FRAG_IDX(wn * 4 + tn, quad, l15)];
#pragma unroll
        for (int tm = 0; tm < 4; ++tm)
          acc[tm][tn] = __builtin_amdgcn_mfma_f32_16x16x32_bf16(af[tm], b0, acc[tm][tn], 0, 0, 0);
      }
    }
#pragma unroll
    for (int tm = 0; tm < 4; ++tm) {
#pragma unroll
      for (int tn = 0; tn < 4; ++tn) {
#pragma unroll
        for (int r = 0; r < 4; ++r) {
          int m = m0 + wm * 64 + tm * 16 + quad * 4 + r;
          int n = n0 + wn * 64 + tn * 16 + l15;
          int b = m >> 10, t = m & 1023, h = n >> 6, f = n & 63;
          vt[(((size_t)(b * 16 + h)) * 64 + f) * 1024 + t] = f2bf(acc[tm][tn][r]);
        }
      }
    }
  }
}

// ---------------------------------------------------------------------------
// Fallback (small workspace): round-4 proj with in-loop split3t.
// ---------------------------------------------------------------------------
__global__ __launch_bounds__(256) void proj_all_mfma(
    const float* __restrict__ x, const ushort* __restrict__ wT,
    float* __restrict__ qf, ushort* __restrict__ kh,
    ushort* __restrict__ km, ushort* __restrict__ kl,
    ushort* __restrict__ vt)
{
  const int zi = blockIdx.z;
  const int m0 = blockIdx.x * 128, n0 = blockIdx.y * 128;
  __shared__ ushort As[3 * 4096];
  __shared__ ushort Bs[3 * 4096];
  const int tid = threadIdx.x;
  const int wave = tid >> 6, lane = tid & 63, l15 = lane & 15, quad = lane >> 4;
  const int wm = wave >> 1, wn = wave & 1;
  const int sr = tid >> 1, q0 = (tid & 1) * 2;
  const int wb0 = FRAG_IDX(sr >> 4, q0, sr & 15);
  const int wb1 = FRAG_IDX(sr >> 4, q0 + 1, sr & 15);
  f32x4 acc[4][4] = {};

  const float* apx = x + (size_t)(m0 + sr) * 1024 + q0 * 8;
  float4 px0 = *(const float4*)(apx);
  float4 px1 = *(const float4*)(apx + 4);
  float4 px2 = *(const float4*)(apx + 8);
  float4 px3 = *(const float4*)(apx + 12);

  if (zi < 2) {
    const ushort* wt = wT + (size_t)zi * 3 * (1u << 20);
    const ushort* bpb = wt + (size_t)(n0 + sr) * 1024 + q0 * 8;
    bf16x8 pb0[3], pb1[3];
#pragma unroll
    for (int s = 0; s < 3; ++s) {
      const ushort* bp = bpb + ((size_t)s << 20);
      pb0[s] = *(const bf16x8*)(bp);
      pb1[s] = *(const bf16x8*)(bp + 8);
    }
    for (int k0 = 0; k0 < 1024; k0 += 32) {
      __syncthreads();
      {
        float xs[16];
        *(float4*)&xs[0]  = px0;
        *(float4*)&xs[4]  = px1;
        *(float4*)&xs[8]  = px2;
        *(float4*)&xs[12] = px3;
        bf16x8 h0, h1, m0v, m1v, l0, l1;
#pragma unroll
        for (int j = 0; j < 8; ++j) {
          ushort hu, mu, lu;
          split3t(xs[j], hu, mu, lu);
          h0[j] = (short)hu; m0v[j] = (short)mu; l0[j] = (short)lu;
          split3t(xs[j + 8], hu, mu, lu);
          h1[j] = (short)hu; m1v[j] = (short)mu; l1[j] = (short)lu;
        }
        *(bf16x8*)&As[wb0] = h0;          *(bf16x8*)&As[wb1] = h1;
        *(bf16x8*)&As[4096 + wb0] = m0v;  *(bf16x8*)&As[4096 + wb1] = m1v;
        *(bf16x8*)&As[8192 + wb0] = l0;   *(bf16x8*)&As[8192 + wb1] = l1;
#pragma unroll
        for (int s = 0; s < 3; ++s) {
          *(bf16x8*)&Bs[s * 4096 + wb0] = pb0[s];
          *(bf16x8*)&Bs[s * 4096 + wb1] = pb1[s];
        }
      }
      __syncthreads();
      if (k0 < 992) {
        const float* nx = apx + k0 + 32;
        px0 = *(const float4*)(nx);
        px1 = *(const float4*)(nx + 4);
        px2 = *(const float4*)(nx + 8);
        px3 = *(const float4*)(nx + 12);
#pragma unroll
        for (int s = 0; s < 3; ++s) {
          const ushort* bp = bpb + ((size_t)s << 20) + k0 + 32;
          pb0[s] = *(const bf16x8*)(bp);
          pb1[s] = *(const bf16x8*)(bp + 8);
        }
      }
      bf16x8 af[4][3];
#pragma unroll
      for (int tm = 0; tm < 4; ++tm)
#pragma unroll
        for (int s = 0; s < 3; ++s)
          af[tm][s] = *(const bf16x8*)&As[s * 4096 + FRAG_IDX(wm * 4 + tm, quad, l15)];
#pragma unroll
      for (int tn = 0; tn < 4; ++tn) {
        const int bi = FRAG_IDX(wn * 4 + tn, quad, l15);
        bf16x8 b0 = *(const bf16x8*)&Bs[bi];
        bf16x8 b1 = *(const bf16x8*)&Bs[4096 + bi];
        bf16x8 b2 = *(const bf16x8*)&Bs[8192 + bi];
#pragma unroll
        for (int tm = 0; tm < 4; ++tm) {
          f32x4 a = acc[tm][tn];
          a = __builtin_amdgcn_mfma_f32_16x16x32_bf16(af[tm][0], b0, a, 0, 0, 0);
          a = __builtin_amdgcn_mfma_f32_16x16x32_bf16(af[tm][0], b1, a, 0, 0, 0);
          a = __builtin_amdgcn_mfma_f32_16x16x32_bf16(af[tm][1], b0, a, 0, 0, 0);
          a = __builtin_amdgcn_mfma_f32_16x16x32_bf16(af[tm][0], b2, a, 0, 0, 0);
          a = __builtin_amdgcn_mfma_f32_16x16x32_bf16(af[tm][1], b1, a, 0, 0, 0);
          a = __builtin_amdgcn_mfma_f32_16x16x32_bf16(af[tm][2], b0, a, 0, 0, 0);
          acc[tm][tn] = a;
        }
      }
    }
#pragma unroll
    for (int tm = 0; tm < 4; ++tm) {
#pragma unroll
      for (int tn = 0; tn < 4; ++tn) {
#pragma unroll
        for (int r = 0; r < 4; ++r) {
          int m = m0 + wm * 64 + tm * 16 + quad * 4 + r;
          int n = n0 + wn * 64 + tn * 16 + l15;
          int b = m >> 10, t = m & 1023, h = n >> 6, f = n & 63;
          size_t idx = (((size_t)(b * 16 + h)) * 1024 + t) * 64 + f;
          if (zi == 0) {
            qf[idx] = acc[tm][tn][r];
          } else {
            ushort hu, mu, lu;
            split3(acc[tm][tn][r], hu, mu, lu);
            kh[idx] = hu; km[idx] = mu; kl[idx] = lu;
          }
        }
      }
    }
  } else {
    const ushort* wt = wT + (size_t)6 * (1u << 20);
    const ushort* bpb = wt + (size_t)(n0 + sr) * 1024 + q0 * 8;
    bf16x8 pb0 = *(const bf16x8*)(bpb);
    bf16x8 pb1 = *(const bf16x8*)(bpb + 8);
    for (int k0 = 0; k0 < 1024; k0 += 32) {
      __syncthreads();
      {
        float xs[16];
        *(float4*)&xs[0]  = px0;
        *(float4*)&xs[4]  = px1;
        *(float4*)&xs[8]  = px2;
        *(float4*)&xs[12] = px3;
        bf16x8 h0, h1;
#pragma unroll
        for (int j = 0; j < 8; ++j) {
          h0[j] = (short)f2bf(xs[j]);
          h1[j] = (short)f2bf(xs[j + 8]);
        }
        *(bf16x8*)&As[wb0] = h0; *(bf16x8*)&As[wb1] = h1;
        *(bf16x8*)&Bs[wb0] = pb0; *(bf16x8*)&Bs[wb1] = pb1;
      }
      __syncthreads();
      if (k0 < 992) {
        const float* nx = apx + k0 + 32;
        px0 = *(const float4*)(nx);
        px1 = *(const float4*)(nx + 4);
        px2 = *(const float4*)(nx + 8);
        px3 = *(const float4*)(nx + 12);
        pb0 = *(const bf16x8*)(bpb + k0 + 32);
        pb1 = *(const bf16x8*)(bpb + k0 + 40);
      }
      bf16x8 af[4];
#pragma unroll
      for (int tm = 0; tm < 4; ++tm)
        af[tm] = *(const bf16x8*)&As[FRAG_IDX(wm * 4 + tm, quad, l15)];
#pragma unroll
      for (int tn = 0; tn < 4; ++tn) {
        bf16x8 b0 = *(const bf16x8*)&Bs[FRAG_IDX(wn * 4 + tn, quad, l15)];
#pragma unroll
        for (int tm = 0; tm < 4; ++tm)
          acc[tm][tn] = __builtin_amdgcn_mfma_f32_16x16x32_bf16(af[tm], b0, acc[tm][tn], 0, 0, 0);
      }
    }
#pragma unroll
    for (int tm = 0; tm < 4; ++tm) {
#pragma unroll
      for (int tn = 0; tn < 4; ++tn) {
#pragma unroll
        for (int r = 0; r < 4; ++r) {
          int m = m0 + wm * 64 + tm * 16 + quad * 4 + r;
          int n = n0 + wn * 64 + tn * 16 + l15;
          int b = m >> 10, t = m & 1023, h = n >> 6, f = n & 63;
          vt[(((size_t)(b * 16 + h)) * 64 + f) * 1024 + t] = f2bf(acc[tm][tn][r]);
        }
      }
    }
  }
}

// ---------------------------------------------------------------------------
// Flash attention (unchanged).
// ---------------------------------------------------------------------------
__global__ __launch_bounds__(512) void attn_mfma(
    const float* __restrict__ qf, const ushort* __restrict__ kh,
    const ushort* __restrict__ km, const ushort* __restrict__ kl,
    const ushort* __restrict__ vt, ushort* __restrict__ zh, ushort* __restrict__ zl)
{
  __shared__ ushort Ks[3][64][68];
  __shared__ ushort Vs[64][68];
  __shared__ ushort Pl[8][16][68];

  const int tid = threadIdx.x;
  const int wave = tid >> 6, lane = tid & 63;
  const int l15 = lane & 15, quad = lane >> 4;
  const int bh = blockIdx.y;
  const int qbase = blockIdx.x * 128;

  bf16x8 aqh[2], aqm[2], aql[2];
  {
    const int qrow = qbase + wave * 16 + l15;
    const float* qp = qf + ((size_t)bh * Tc + qrow) * Fc;
#pragma unroll
    for (int ks = 0; ks < 2; ++ks) {
      int f0 = ks * 32 + quad * 8;
      float4 x0 = *(const float4*)(qp + f0);
      float4 x1 = *(const float4*)(qp + f0 + 4);
      float xs[8] = {x0.x, x0.y, x0.z, x0.w, x1.x, x1.y, x1.z, x1.w};
#pragma unroll
      for (int j = 0; j < 8; ++j) {
        ushort hu, mu, lu;
        split3(xs[j], hu, mu, lu);
        aqh[ks][j] = (short)hu; aqm[ks][j] = (short)mu; aql[ks][j] = (short)lu;
      }
    }
  }

  f32x4 o[4] = {{0,0,0,0},{0,0,0,0},{0,0,0,0},{0,0,0,0}};
  float m_run[4], l_run[4];
#pragma unroll
  for (int r = 0; r < 4; ++r) { m_run[r] = -1e30f; l_run[r] = 0.f; }

  const int srow = tid >> 3, sc8 = tid & 7;
  const size_t kbase = (size_t)bh * Tc * Fc;
  const size_t vbase = (size_t)bh * Fc * Tc;
  const ushort* kp0 = kh + kbase + (size_t)srow * Fc + sc8 * 8;
  const ushort* kp1 = km + kbase + (size_t)srow * Fc + sc8 * 8;
  const ushort* kp2 = kl + kbase + (size_t)srow * Fc + sc8 * 8;
  const ushort* vp  = vt + vbase + (size_t)srow * Tc + sc8 * 8;

  for (int kt = 0; kt < Tc; kt += 64) {
    __syncthreads();
    {
      const size_t ko = (size_t)kt * Fc;
      *(bf16x8*)&Ks[0][srow][sc8 * 8] = *(const bf16x8*)(kp0 + ko);
      *(bf16x8*)&Ks[1][srow][sc8 * 8] = *(const bf16x8*)(kp1 + ko);
      *(bf16x8*)&Ks[2][srow][sc8 * 8] = *(const bf16x8*)(kp2 + ko);
      *(bf16x8*)&Vs[srow][sc8 * 8]    = *(const bf16x8*)(vp + kt);
    }
    __syncthreads();

    f32x4 sacc[4] = {{0,0,0,0},{0,0,0,0},{0,0,0,0},{0,0,0,0}};
#pragma unroll
    for (int nt = 0; nt < 4; ++nt) {
      int key = nt * 16 + l15;
#pragma unroll
      for (int ks = 0; ks < 2; ++ks) {
        int f0 = ks * 32 + quad * 8;
        bf16x8 bh_ = *(const bf16x8*)&Ks[0][key][f0];
        bf16x8 bm_ = *(const bf16x8*)&Ks[1][key][f0];
        bf16x8 bl_ = *(const bf16x8*)&Ks[2][key][f0];
        sacc[nt] = __builtin_amdgcn_mfma_f32_16x16x32_bf16(aqh[ks], bh_, sacc[nt], 0, 0, 0);
        sacc[nt] = __builtin_amdgcn_mfma_f32_16x16x32_bf16(aqh[ks], bm_, sacc[nt], 0, 0, 0);
        sacc[nt] = __builtin_amdgcn_mfma_f32_16x16x32_bf16(aqm[ks], bh_, sacc[nt], 0, 0, 0);
        sacc[nt] = __builtin_amdgcn_mfma_f32_16x16x32_bf16(aqh[ks], bl_, sacc[nt], 0, 0, 0);
        sacc[nt] = __builtin_amdgcn_mfma_f32_16x16x32_bf16(aqm[ks], bm_, sacc[nt], 0, 0, 0);
        sacc[nt] = __builtin_amdgcn_mfma_f32_16x16x32_bf16(aql[ks], bh_, sacc[nt], 0, 0, 0);
      }
    }

    const int rowg0 = qbase + wave * 16 + quad * 4;
    float mx[4];
#pragma unroll
    for (int r = 0; r < 4; ++r) mx[r] = -1e30f;
#pragma unroll
    for (int nt = 0; nt < 4; ++nt) {
      int key = kt + nt * 16 + l15;
#pragma unroll
      for (int r = 0; r < 4; ++r) {
        float s = sacc[nt][r];
        if (key > rowg0 + r) s *= -1.0e9f + 1.0f;
        s *= 0.125f;
        sacc[nt][r] = s;
        mx[r] = fmaxf(mx[r], s);
      }
    }
#pragma unroll
    for (int r = 0; r < 4; ++r)
#pragma unroll
      for (int d = 1; d < 16; d <<= 1) mx[r] = fmaxf(mx[r], __shfl_xor(mx[r], d));

    float corr[4], ps[4];
#pragma unroll
    for (int r = 0; r < 4; ++r) {
      float m2 = fmaxf(m_run[r], mx[r]);
      corr[r] = __expf(m_run[r] - m2);
      m_run[r] = m2;
      ps[r] = 0.f;
    }
#pragma unroll
    for (int nt = 0; nt < 4; ++nt) {
#pragma unroll
      for (int r = 0; r < 4; ++r) {
        float p = __expf(sacc[nt][r] - m_run[r]);
        ps[r] += p;
        Pl[wave][quad * 4 + r][nt * 16 + l15] = f2bf(p);
      }
    }
#pragma unroll
    for (int r = 0; r < 4; ++r) {
#pragma unroll
      for (int d = 1; d < 16; d <<= 1) ps[r] += __shfl_xor(ps[r], d);
      l_run[r] = l_run[r] * corr[r] + ps[r];
#pragma unroll
      for (int ft = 0; ft < 4; ++ft) o[ft][r] *= corr[r];
    }

#pragma unroll
    for (int ks2 = 0; ks2 < 2; ++ks2) {
      bf16x8 pa = *(const bf16x8*)&Pl[wave][l15][ks2 * 32 + quad * 8];
#pragma unroll
      for (int ft = 0; ft < 4; ++ft) {
        bf16x8 vb = *(const bf16x8*)&Vs[ft * 16 + l15][ks2 * 32 + quad * 8];
        o[ft] = __builtin_amdgcn_mfma_f32_16x16x32_bf16(pa, vb, o[ft], 0, 0, 0);
      }
    }
  }

  const int b = bh >> 4, h = bh & 15;
#pragma unroll
  for (int r = 0; r < 4; ++r) {
    float inv = 1.f / l_run[r];
    int row = qbase + wave * 16 + quad * 4 + r;
    size_t base = ((size_t)(b * Tc + row)) * Ec + h * Fc;
#pragma unroll
    for (int ft = 0; ft < 4; ++ft) {
      ushort hu, lu;
      split2(o[ft][r] * inv, hu, lu);
      zh[base + ft * 16 + l15] = hu;
      zl[base + ft * 16 + l15] = lu;
    }
  }
}

// ---------------------------------------------------------------------------
// fr GEMM: tile 128x64. Round 6: wave-linear staging chunks (conflict-free
// writes); reg-prefetch in compute phase.
// ---------------------------------------------------------------------------
__global__ __launch_bounds__(256) void gemm_fr_mfma(
    const ushort* __restrict__ zh, const ushort* __restrict__ zl,
    const ushort* __restrict__ frT, const float* __restrict__ x,
    float* __restrict__ s1, float2* __restrict__ part)
{
  const int bb = blockIdx.z;
  const int m0 = blockIdx.x * 128, n0 = blockIdx.y * 64;
  __shared__ ushort Ah[4096], Al[4096], Bh[2048], Bl[2048];
  __shared__ float2 red[256];
  const int tid = threadIdx.x;
  const int wave = tid >> 6, lane = tid & 63, l15 = lane & 15, quad = lane >> 4;
  const int wm = wave >> 1, wn = wave & 1;
  const int ac1 = (wave * 64 + lane) * 8, ac2 = ac1 + 2048;
  f32x4 acc[4][2] = {};
  const size_t abase1 = ((size_t)bb * 1024 + m0 + wave * 16 + l15) * 1024 + quad * 8;
  const size_t abase2 = abase1 + (size_t)64 * 1024;
  const size_t bbase = ((size_t)bb * 1024 + n0 + wave * 16 + l15) * 1024 + quad * 8;
  const ushort* blp = frT + (4u << 20);
  bf16x8 pAh0 = *(const bf16x8*)(zh + abase1);
  bf16x8 pAh1 = *(const bf16x8*)(zh + abase2);
  bf16x8 pAl0 = *(const bf16x8*)(zl + abase1);
  bf16x8 pAl1 = *(const bf16x8*)(zl + abase2);
  bf16x8 pBh  = *(const bf16x8*)(frT + bbase);
  bf16x8 pBl  = *(const bf16x8*)(blp + bbase);
  for (int k0 = 0; k0 < 1024; k0 += 32) {
    __syncthreads();
    {
      *(bf16x8*)&Ah[ac1] = pAh0;
      *(bf16x8*)&Ah[ac2] = pAh1;
      *(bf16x8*)&Al[ac1] = pAl0;
      *(bf16x8*)&Al[ac2] = pAl1;
      *(bf16x8*)&Bh[ac1] = pBh;
      *(bf16x8*)&Bl[ac1] = pBl;
    }
    __syncthreads();
    if (k0 < 992) {
      pAh0 = *(const bf16x8*)(zh + abase1 + k0 + 32);
      pAh1 = *(const bf16x8*)(zh + abase2 + k0 + 32);
      pAl0 = *(const bf16x8*)(zl + abase1 + k0 + 32);
      pAl1 = *(const bf16x8*)(zl + abase2 + k0 + 32);
      pBh  = *(const bf16x8*)(frT + bbase + k0 + 32);
      pBl  = *(const bf16x8*)(blp + bbase + k0 + 32);
    }
    bf16x8 ah[4], al[4];
#pragma unroll
    for (int tm = 0; tm < 4; ++tm) {
      ah[tm] = *(const bf16x8*)&Ah[FRAG_IDX(wm * 4 + tm, quad, l15)];
      al[tm] = *(const bf16x8*)&Al[FRAG_IDX(wm * 4 + tm, quad, l15)];
    }
#pragma unroll
    for (int tn = 0; tn < 2; ++tn) {
      const int bi = FRAG_IDX(wn * 2 + tn, quad, l15);
      bf16x8 b0 = *(const bf16x8*)&Bh[bi];
      bf16x8 b1 = *(const bf16x8*)&Bl[bi];
#pragma unroll
      for (int tm = 0; tm < 4; ++tm) {
        f32x4 a = acc[tm][tn];
        a = __builtin_amdgcn_mfma_f32_16x16x32_bf16(ah[tm], b0, a, 0, 0, 0);
        a = __builtin_amdgcn_mfma_f32_16x16x32_bf16(ah[tm], b1, a, 0, 0, 0);
        a = __builtin_amdgcn_mfma_f32_16x16x32_bf16(al[tm], b0, a, 0, 0, 0);
        acc[tm][tn] = a;
      }
    }
  }
  float sum = 0.f, sq = 0.f;
#pragma unroll
  for (int tm = 0; tm < 4; ++tm) {
#pragma unroll
    for (int tn = 0; tn < 2; ++tn) {
#pragma unroll
      for (int r = 0; r < 4; ++r) {
        int m = m0 + wm * 64 + tm * 16 + quad * 4 + r;
        int n = n0 + wn * 32 + tn * 16 + l15;
        size_t idx = ((size_t)bb * 1024 + m) * 1024 + n;
        float o = x[idx] + acc[tm][tn][r];
        s1[idx] = o;
        sum += o; sq += o * o;
      }
    }
  }
  red[tid] = make_float2(sum, sq);
  __syncthreads();
  for (int s = 128; s > 0; s >>= 1) {
    if (tid < s) { red[tid].x += red[tid + s].x; red[tid].y += red[tid + s].y; }
    __syncthreads();
  }
  if (tid == 0) part[bb * 128 + blockIdx.x * 16 + blockIdx.y] = red[0];
}

// ---------------------------------------------------------------------------
// ff GEMM: tile 128x64. Round 6: wave-linear staging chunks.
// ---------------------------------------------------------------------------
__global__ __launch_bounds__(256) void gemm_ff_mfma(
    const ushort* __restrict__ z1h, const ushort* __restrict__ z1l,
    const ushort* __restrict__ fwh, const ushort* __restrict__ fwl,
    const float* __restrict__ ffb, float* __restrict__ s2,
    float2* __restrict__ part)
{
  const int m0 = blockIdx.x * 128, n0 = blockIdx.y * 64;
  __shared__ ushort Ah[4096], Al[4096], Bh[2048], Bl[2048];
  __shared__ float2 red[256];
  const int tid = threadIdx.x;
  const int wave = tid >> 6, lane = tid & 63, l15 = lane & 15, quad = lane >> 4;
  const int wm = wave >> 1, wn = wave & 1;
  const int ac1 = (wave * 64 + lane) * 8, ac2 = ac1 + 2048;
  f32x4 acc[4][2] = {};
  const size_t abase1 = (size_t)(m0 + wave * 16 + l15) * 1024 + quad * 8;
  const size_t abase2 = abase1 + (size_t)64 * 1024;
  const size_t bbase = (size_t)(n0 + wave * 16 + l15) * 1024 + quad * 8;
  bf16x8 pAh0 = *(const bf16x8*)(z1h + abase1);
  bf16x8 pAh1 = *(const bf16x8*)(z1h + abase2);
  bf16x8 pAl0 = *(const bf16x8*)(z1l + abase1);
  bf16x8 pAl1 = *(const bf16x8*)(z1l + abase2);
  bf16x8 pBh  = *(const bf16x8*)(fwh + bbase);
  bf16x8 pBl  = *(const bf16x8*)(fwl + bbase);
  for (int k0 = 0; k0 < 1024; k0 += 32) {
    __syncthreads();
    {
      *(bf16x8*)&Ah[ac1] = pAh0;
      *(bf16x8*)&Ah[ac2] = pAh1;
      *(bf16x8*)&Al[ac1] = pAl0;
      *(bf16x8*)&Al[ac2] = pAl1;
      *(bf16x8*)&Bh[ac1] = pBh;
      *(bf16x8*)&Bl[ac1] = pBl;
    }
    __syncthreads();
    if (k0 < 992) {
      pAh0 = *(const bf16x8*)(z1h + abase1 + k0 + 32);
      pAh1 = *(const bf16x8*)(z1h + abase2 + k0 + 32);
      pAl0 = *(const bf16x8*)(z1l + abase1 + k0 + 32);
      pAl1 = *(const bf16x8*)(z1l + abase2 + k0 + 32);
      pBh  = *(const bf16x8*)(fwh + bbase + k0 + 32);
      pBl  = *(const bf16x8*)(fwl + bbase + k0 + 32);
    }
    bf16x8 ah[4], al[4];
#pragma unroll
    for (int tm = 0; tm < 4; ++tm) {
      ah[tm] = *(const bf16x8*)&Ah[FRAG_IDX(wm * 4 + tm, quad, l15)];
      al[tm] = *(const bf16x8*)&Al[FRAG_IDX(wm * 4 + tm, quad, l15)];
    }
#pragma unroll
    for (int tn = 0; tn < 2; ++tn) {
      const int bi = FRAG_IDX(wn * 2 + tn, quad, l15);
      bf16x8 b0 = *(const bf16x8*)&Bh[bi];
      bf16x8 b1 = *(const bf16x8*)&Bl[bi];
#pragma unroll
      for (int tm = 0; tm < 4; ++tm) {
        f32x4 a = acc[tm][tn];
        a = __builtin_amdgcn_mfma_f32_16x16x32_bf16(ah[tm], b0, a, 0, 0, 0);
        a = __builtin_amdgcn_mfma_f32_16x16x32_bf16(ah[tm], b1, a, 0, 0, 0);
        a = __builtin_amdgcn_mfma_f32_16x16x32_bf16(al[tm], b0, a, 0, 0, 0);
        acc[tm][tn] = a;
      }
    }
  }
  float sum = 0.f, sq = 0.f;
#pragma unroll
  for (int tm = 0; tm < 4; ++tm) {
#pragma unroll
    for (int tn = 0; tn < 2; ++tn) {
#pragma unroll
      for (int r = 0; r < 4; ++r) {
        int m = m0 + wm * 64 + tm * 16 + quad * 4 + r;
        int n = n0 + wn * 32 + tn * 16 + l15;
        size_t idx = (size_t)m * 1024 + n;
        float z1v = bf2f(z1h[idx]) + bf2f(z1l[idx]);
        float o = z1v + fmaxf(acc[tm][tn][r] + ffb[n], 0.f);
        s2[idx] = o;
        sum += o; sq += o * o;
      }
    }
  }
  red[tid] = make_float2(sum, sq);
  __syncthreads();
  for (int s = 128; s > 0; s >>= 1) {
    if (tid < s) { red[tid].x += red[tid + s].x; red[tid].y += red[tid + s].y; }
    __syncthreads();
  }
  if (tid == 0) part[blockIdx.x * 16 + blockIdx.y] = red[0];
}

__global__ __launch_bounds__(256) void ln_stats(
    const float2* __restrict__ part, float2* __restrict__ stats, int npart)
{
  __shared__ double sd[256], sq[256];
  const int tid = threadIdx.x;
  double as = 0.0, aq = 0.0;
  for (int i = tid; i < npart; i += 256) {
    float2 p = part[blockIdx.x * npart + i];
    as += (double)p.x; aq += (double)p.y;
  }
  sd[tid] = as; sq[tid] = aq;
  __syncthreads();
  for (int s = 128; s > 0; s >>= 1) {
    if (tid < s) { sd[tid] += sd[tid + s]; sq[tid] += sq[tid + s]; }
    __syncthreads();
  }
  if (tid == 0) {
    const double n = (double)Tc * Ec;
    double mean = sd[0] / n;
    double var = sq[0] / n - mean * mean;
    if (var < 0.0) var = 0.0;
    double rs = 1.0 / sqrt(var + 1e-5);
    stats[blockIdx.x] = make_float2((float)mean, (float)rs);
  }
}

// ln_norm -> split2 pair; blocks >= 4096 instead split2 ffw (folded launch).
__global__ __launch_bounds__(256) void ln_norm_split(
    const float* __restrict__ s, const float2* __restrict__ stats,
    const float* __restrict__ w, const float* __restrict__ bias,
    ushort* __restrict__ oh, ushort* __restrict__ ol,
    const float* __restrict__ ffw, ushort* __restrict__ fwh, ushort* __restrict__ fwl)
{
  if (blockIdx.x >= 4096) {
    int i = (blockIdx.x - 4096) * 256 + threadIdx.x;
#pragma unroll
    for (int j = 0; j < 4; ++j) {
      int idx = i * 4 + j;
      float4 v = ((const float4*)ffw)[idx];
      ushort4 h, l;
      split2(v.x, h.x, l.x); split2(v.y, h.y, l.y);
      split2(v.z, h.z, l.z); split2(v.w, h.w, l.w);
      ((ushort4*)fwh)[idx] = h; ((ushort4*)fwl)[idx] = l;
    }
    return;
  }
  int i = blockIdx.x * 256 + threadIdx.x;
  int b = i >> 18;
  int te4 = i & ((1 << 18) - 1);
  float2 st = stats[b];
  float4 sv = ((const float4*)s)[i];
  float4 wv = ((const float4*)w)[te4];
  float4 bv = ((const float4*)bias)[te4];
  float4 o;
  o.x = (sv.x - st.x) * st.y * wv.x + bv.x;
  o.y = (sv.y - st.x) * st.y * wv.y + bv.y;
  o.z = (sv.z - st.x) * st.y * wv.z + bv.z;
  o.w = (sv.w - st.x) * st.y * wv.w + bv.w;
  ushort4 h, l;
  split2(o.x, h.x, l.x); split2(o.y, h.y, l.y);
  split2(o.z, h.z, l.z); split2(o.w, h.w, l.w);
  ((ushort4*)oh)[i] = h; ((ushort4*)ol)[i] = l;
}

__global__ __launch_bounds__(256) void ln_norm(
    const float* __restrict__ s, const float2* __restrict__ stats,
    const float* __restrict__ w, const float* __restrict__ bias,
    float* __restrict__ out)
{
  int i = blockIdx.x * 256 + threadIdx.x;
  if (i >= (Bc * Tc * Ec) / 4) return;
  int b = i >> 18;
  int te4 = i & ((1 << 18) - 1);
  float2 st = stats[b];
  float4 sv = ((const float4*)s)[i];
  float4 wv = ((const float4*)w)[te4];
  float4 bv = ((const float4*)bias)[te4];
  float4 o;
  o.x = (sv.x - st.x) * st.y * wv.x + bv.x;
  o.y = (sv.y - st.x) * st.y * wv.y + bv.y;
  o.z = (sv.z - st.x) * st.y * wv.z + bv.z;
  o.w = (sv.w - st.x) * st.y * wv.w + bv.w;
  ((float4*)out)[i] = o;
}

// ---------------------------------------------------------------------------
extern "C" void kernel_launch(void* const* d_in, const int* in_sizes, int n_in,
                              void* d_out, int out_size, void* d_ws, size_t ws_size,
                              hipStream_t stream)
{
  const float* x    = (const float*)d_in[0];
  const float* qw   = (const float*)d_in[1];
  const float* kw   = (const float*)d_in[2];
  const float* vw   = (const float*)d_in[3];
  const float* frw  = (const float*)d_in[4];
  const float* ffw  = (const float*)d_in[5];
  const float* ffb  = (const float*)d_in[6];
  const float* ln1w = (const float*)d_in[7];
  const float* ln1b = (const float*)d_in[8];
  const float* ln2w = (const float*)d_in[9];
  const float* ln2b = (const float*)d_in[10];
  float* out = (float*)d_out;
  char* W = (char*)d_ws;

  const size_t MB = 1ull << 20;
  float*  qf  = (float*)(W);
  ushort* kh  = (ushort*)(W + 16 * MB);
  ushort* km  = (ushort*)(W + 24 * MB);
  ushort* kl  = (ushort*)(W + 32 * MB);
  ushort* vt  = (ushort*)(W + 40 * MB);
  ushort* wT  = (ushort*)(W + 48 * MB);
  ushort* zh  = (ushort*)(W + 48 * MB);
  ushort* zl  = (ushort*)(W + 56 * MB);
  ushort* frT = (ushort*)(W + 16 * MB);
  float*  s1  = (float*)(W);
  ushort* z1h = (ushort*)(W + 16 * MB);
  ushort* z1l = (ushort*)(W + 24 * MB);
  ushort* fwh = (ushort*)(W + 48 * MB);
  ushort* fwl = (ushort*)(W + 50 * MB);
  float*  s2  = (float*)(W + 32 * MB);
  float2* part1  = (float2*)(W + 64 * MB);
  float2* part2  = part1 + 1024;
  float2* stats1 = part2 + 1024;
  float2* stats2 = stats1 + 4;
  // x pre-split planes (only used when workspace permits)
  ushort* xh = (ushort*)(W + 65 * MB);
  ushort* xm = (ushort*)(W + 73 * MB);
  ushort* xl = (ushort*)(W + 81 * MB);
  const bool big_ws = ws_size >= 90 * MB;

  if (big_ws) {
    // z<3: weight transpose+split; z>=3: x_split (8 z-slices x 256 blocks)
    prep_all<<<dim3(16, 16, 11), 256, 0, stream>>>(qw, kw, vw, wT, x, xh, xm, xl);
    proj_all_ps<<<dim3(32, 8, 3), 256, 0, stream>>>(xh, xm, xl, wT, qf, kh, km, kl, vt);
  } else {
    prep_all<<<dim3(16, 16, 3), 256, 0, stream>>>(qw, kw, vw, wT, x, xh, xm, xl);
    proj_all_mfma<<<dim3(32, 8, 3), 256, 0, stream>>>(x, wT, qf, kh, km, kl, vt);
  }
  attn_mfma<<<dim3(8, 64), 512, 0, stream>>>(qf, kh, km, kl, vt, zh, zl);
  transp_frw<<<dim3(16, 16, 4), 256, 0, stream>>>(frw, frT);
  gemm_fr_mfma<<<dim3(8, 16, 4), 256, 0, stream>>>(zh, zl, frT, x, s1, part1);
  ln_stats<<<dim3(4), 256, 0, stream>>>(part1, stats1, 128);
  ln_norm_split<<<dim3(4352), 256, 0, stream>>>(s1, stats1, ln1w, ln1b, z1h, z1l,
                                                ffw, fwh, fwl);
  gemm_ff_mfma<<<dim3(32, 16), 256, 0, stream>>>(z1h, z1l, fwh, fwl, ffb, s2, part2);
  ln_stats<<<dim3(4), 256, 0, stream>>>(part2, stats2, 128);
  ln_norm<<<dim3(4096), 256, 0, stream>>>(s2, stats2, ln2w, ln2b, out);
}

// Round 7
// 414.587 us; speedup vs baseline: 1.0895x; 1.0895x over previous
//
#include <hip/hip_runtime.h>
#include <math.h>

constexpr int Bc = 4, Tc = 1024, Ec = 1024, Hc = 16, Fc = 64;

typedef __attribute__((ext_vector_type(8))) short bf16x8;
typedef __attribute__((ext_vector_type(4))) float f32x4;

__device__ __forceinline__ ushort f2bf(float x) {
  union { float f; unsigned u; } v; v.f = x;
  unsigned r = v.u + 0x7fffu + ((v.u >> 16) & 1u);
  return (ushort)(r >> 16);
}
__device__ __forceinline__ float bf2f(ushort h) {
  union { float f; unsigned u; } v; v.u = ((unsigned)h) << 16; return v.f;
}
__device__ __forceinline__ void split3(float x, ushort& h, ushort& m, ushort& l) {
  h = f2bf(x);
  float r1 = x - bf2f(h);
  m = f2bf(r1);
  float r2 = r1 - bf2f(m);
  l = f2bf(r2);
}
__device__ __forceinline__ void split2(float x, ushort& h, ushort& l) {
  h = f2bf(x);
  l = f2bf(x - bf2f(h));
}
// Truncation split3 (~8 VALU ops): one-sided residual < 2^-22 rel.
__device__ __forceinline__ void split3t(float x, ushort& h, ushort& m, ushort& l) {
  union { float f; unsigned u; } v; v.f = x;
  h = (ushort)(v.u >> 16);
  union { float f; unsigned u; } hf; hf.u = v.u & 0xffff0000u;
  float r1 = x - hf.f;
  union { float f; unsigned u; } v1; v1.f = r1;
  m = (ushort)(v1.u >> 16);
  union { float f; unsigned u; } mf; mf.u = v1.u & 0xffff0000u;
  float r2 = r1 - mf.f;
  union { float f; unsigned u; } v2; v2.f = r2;
  l = (ushort)(v2.u >> 16);
}

// Fragment-major LDS cell: [tile][quad(0..3)][lane(0..15)][8 ushorts]
// NOTE (rounds 2+6, measured): do NOT replace the sr/q0 scatter staging with
// wave-linear "conflict-free" chunks. The 7.34M LDS write conflicts are
// hidden under multi-wave overlap; the wave-linear variant doubles distinct
// cache lines per thread (12 vs 6) and regresses proj by ~20%.
#define FRAG_IDX(tile, quad, l) (((((tile) * 4) + (quad)) * 16 + (l)) * 8)

// ---------------------------------------------------------------------------
// Merged prep: z<3 = transpose+split projection weights; z>=3 = x_split.
// One dispatch instead of two serial ones (independent work, disjoint ws).
// ---------------------------------------------------------------------------
__global__ __launch_bounds__(256) void prep_all(
    const float* __restrict__ qw, const float* __restrict__ kw,
    const float* __restrict__ vw, ushort* __restrict__ wT,
    const float* __restrict__ x, ushort* __restrict__ xh,
    ushort* __restrict__ xm, ushort* __restrict__ xl)
{
  const int zi = blockIdx.z;
  const int tid = threadIdx.x;
  if (zi >= 3) {
    // x_split: one-time split3t of x into three bf16 planes.
    const int bid = (zi - 3) * 256 + blockIdx.y * 16 + blockIdx.x;
    const int i = bid * 256 + tid;  // 8 elements per thread
    const float4 a = ((const float4*)x)[i * 2];
    const float4 b = ((const float4*)x)[i * 2 + 1];
    const float xs[8] = {a.x, a.y, a.z, a.w, b.x, b.y, b.z, b.w};
    bf16x8 h, m, l;
#pragma unroll
    for (int j = 0; j < 8; ++j) {
      ushort hu, mu, lu;
      split3t(xs[j], hu, mu, lu);
      h[j] = (short)hu; m[j] = (short)mu; l[j] = (short)lu;
    }
    ((bf16x8*)xh)[i] = h;
    ((bf16x8*)xm)[i] = m;
    ((bf16x8*)xl)[i] = l;
    return;
  }
  const float* src = (zi == 0) ? qw : (zi == 1) ? kw : vw;
  ushort* dst = wT + (size_t)(zi * 3) * (1u << 20);
  const int ns = (zi == 2) ? 1 : 3;
  const int h = blockIdx.y, e0 = blockIdx.x * 64;
  __shared__ float T[64][68];
  {
    const int er = tid >> 4, fr = (tid & 15) * 4;
#pragma unroll
    for (int i = 0; i < 4; ++i) {
      const float4 v = *(const float4*)&src[((size_t)(h * 1024 + e0 + er + i * 16)) * 64 + fr];
      *(float4*)&T[er + i * 16][fr] = v;
    }
  }
  __syncthreads();
  const int f = tid >> 2, eo = (tid & 3) * 16;
  ushort hs[16], ms[16], ls[16];
#pragma unroll
  for (int j = 0; j < 16; ++j) split3(T[eo + j][f], hs[j], ms[j], ls[j]);
  const size_t nbase = (size_t)(h * 64 + f) * 1024 + e0 + eo;
  bf16x8 v0, v1;
#pragma unroll
  for (int j = 0; j < 8; ++j) { v0[j] = (short)hs[j]; v1[j] = (short)hs[j + 8]; }
  *(bf16x8*)&dst[nbase] = v0; *(bf16x8*)&dst[nbase + 8] = v1;
  if (ns == 3) {
#pragma unroll
    for (int j = 0; j < 8; ++j) { v0[j] = (short)ms[j]; v1[j] = (short)ms[j + 8]; }
    *(bf16x8*)&dst[(1u << 20) + nbase] = v0; *(bf16x8*)&dst[(1u << 20) + nbase + 8] = v1;
#pragma unroll
    for (int j = 0; j < 8; ++j) { v0[j] = (short)ls[j]; v1[j] = (short)ls[j + 8]; }
    *(bf16x8*)&dst[(2u << 20) + nbase] = v0; *(bf16x8*)&dst[(2u << 20) + nbase + 8] = v1;
  }
}

// ---------------------------------------------------------------------------
// Pre-transpose + split2 fr weights.
// ---------------------------------------------------------------------------
__global__ __launch_bounds__(256) void transp_frw(
    const float* __restrict__ frw, ushort* __restrict__ frT)
{
  const int bb = blockIdx.z;
  const int e0 = blockIdx.x * 64, d0 = blockIdx.y * 64;
  __shared__ float T[64][68];
  const int tid = threadIdx.x;
  {
    const int er = tid >> 4, dr = (tid & 15) * 4;
#pragma unroll
    for (int i = 0; i < 4; ++i) {
      const float4 v = *(const float4*)&frw[((size_t)bb * 1024 + e0 + er + i * 16) * 1024 + d0 + dr];
      *(float4*)&T[er + i * 16][dr] = v;
    }
  }
  __syncthreads();
  const int d = tid >> 2, eo = (tid & 3) * 16;
  ushort hs[16], ls[16];
#pragma unroll
  for (int j = 0; j < 16; ++j) split2(T[eo + j][d], hs[j], ls[j]);
  const size_t nbase = ((size_t)bb * 1024 + d0 + d) * 1024 + e0 + eo;
  bf16x8 v0, v1;
#pragma unroll
  for (int j = 0; j < 8; ++j) { v0[j] = (short)hs[j]; v1[j] = (short)hs[j + 8]; }
  *(bf16x8*)&frT[nbase] = v0; *(bf16x8*)&frT[nbase + 8] = v1;
#pragma unroll
  for (int j = 0; j < 8; ++j) { v0[j] = (short)ls[j]; v1[j] = (short)ls[j + 8]; }
  *(bf16x8*)&frT[(4u << 20) + nbase] = v0; *(bf16x8*)&frT[(4u << 20) + nbase + 8] = v1;
}

// ---------------------------------------------------------------------------
// Projections from pre-split x planes (round-5 proven version). Staging =
// sr/q0 FRAG_IDX scatter (1 cache line per thread-pair); A and B fragments
// reg-prefetched in the compute phase.
// ---------------------------------------------------------------------------
__global__ __launch_bounds__(256) void proj_all_ps(
    const ushort* __restrict__ xh, const ushort* __restrict__ xm,
    const ushort* __restrict__ xl, const ushort* __restrict__ wT,
    float* __restrict__ qf, ushort* __restrict__ kh,
    ushort* __restrict__ km, ushort* __restrict__ kl,
    ushort* __restrict__ vt)
{
  const int zi = blockIdx.z;
  const int m0 = blockIdx.x * 128, n0 = blockIdx.y * 128;
  __shared__ ushort As[3 * 4096];
  __shared__ ushort Bs[3 * 4096];
  const int tid = threadIdx.x;
  const int wave = tid >> 6, lane = tid & 63, l15 = lane & 15, quad = lane >> 4;
  const int wm = wave >> 1, wn = wave & 1;
  const int sr = tid >> 1, q0 = (tid & 1) * 2;
  const int wb0 = FRAG_IDX(sr >> 4, q0, sr & 15);
  const int wb1 = FRAG_IDX(sr >> 4, q0 + 1, sr & 15);
  f32x4 acc[4][4] = {};

  const size_t arow = (size_t)(m0 + sr) * 1024 + q0 * 8;
  const ushort* axh = xh + arow;
  const ushort* axm = xm + arow;
  const ushort* axl = xl + arow;

  if (zi < 2) {
    const ushort* wt = wT + (size_t)zi * 3 * (1u << 20);
    const ushort* bpb = wt + (size_t)(n0 + sr) * 1024 + q0 * 8;
    // current-window fragments in registers
    bf16x8 pah0 = *(const bf16x8*)(axh);
    bf16x8 pah1 = *(const bf16x8*)(axh + 8);
    bf16x8 pam0 = *(const bf16x8*)(axm);
    bf16x8 pam1 = *(const bf16x8*)(axm + 8);
    bf16x8 pal0 = *(const bf16x8*)(axl);
    bf16x8 pal1 = *(const bf16x8*)(axl + 8);
    bf16x8 pb0[3], pb1[3];
#pragma unroll
    for (int s = 0; s < 3; ++s) {
      const ushort* bp = bpb + ((size_t)s << 20);
      pb0[s] = *(const bf16x8*)(bp);
      pb1[s] = *(const bf16x8*)(bp + 8);
    }
    for (int k0 = 0; k0 < 1024; k0 += 32) {
      __syncthreads();
      {
        *(bf16x8*)&As[wb0] = pah0;        *(bf16x8*)&As[wb1] = pah1;
        *(bf16x8*)&As[4096 + wb0] = pam0; *(bf16x8*)&As[4096 + wb1] = pam1;
        *(bf16x8*)&As[8192 + wb0] = pal0; *(bf16x8*)&As[8192 + wb1] = pal1;
#pragma unroll
        for (int s = 0; s < 3; ++s) {
          *(bf16x8*)&Bs[s * 4096 + wb0] = pb0[s];
          *(bf16x8*)&Bs[s * 4096 + wb1] = pb1[s];
        }
      }
      __syncthreads();
      // Prefetch next window in the compute phase (latency hidden under MFMA)
      if (k0 < 992) {
        const int ko = k0 + 32;
        pah0 = *(const bf16x8*)(axh + ko);
        pah1 = *(const bf16x8*)(axh + ko + 8);
        pam0 = *(const bf16x8*)(axm + ko);
        pam1 = *(const bf16x8*)(axm + ko + 8);
        pal0 = *(const bf16x8*)(axl + ko);
        pal1 = *(const bf16x8*)(axl + ko + 8);
#pragma unroll
        for (int s = 0; s < 3; ++s) {
          const ushort* bp = bpb + ((size_t)s << 20) + ko;
          pb0[s] = *(const bf16x8*)(bp);
          pb1[s] = *(const bf16x8*)(bp + 8);
        }
      }
      bf16x8 af[4][3];
#pragma unroll
      for (int tm = 0; tm < 4; ++tm)
#pragma unroll
        for (int s = 0; s < 3; ++s)
          af[tm][s] = *(const bf16x8*)&As[s * 4096 + FRAG_IDX(wm * 4 + tm, quad, l15)];
#pragma unroll
      for (int tn = 0; tn < 4; ++tn) {
        const int bi = FRAG_IDX(wn * 4 + tn, quad, l15);
        bf16x8 b0 = *(const bf16x8*)&Bs[bi];
        bf16x8 b1 = *(const bf16x8*)&Bs[4096 + bi];
        bf16x8 b2 = *(const bf16x8*)&Bs[8192 + bi];
#pragma unroll
        for (int tm = 0; tm < 4; ++tm) {
          f32x4 a = acc[tm][tn];
          a = __builtin_amdgcn_mfma_f32_16x16x32_bf16(af[tm][0], b0, a, 0, 0, 0);
          a = __builtin_amdgcn_mfma_f32_16x16x32_bf16(af[tm][0], b1, a, 0, 0, 0);
          a = __builtin_amdgcn_mfma_f32_16x16x32_bf16(af[tm][1], b0, a, 0, 0, 0);
          a = __builtin_amdgcn_mfma_f32_16x16x32_bf16(af[tm][0], b2, a, 0, 0, 0);
          a = __builtin_amdgcn_mfma_f32_16x16x32_bf16(af[tm][1], b1, a, 0, 0, 0);
          a = __builtin_amdgcn_mfma_f32_16x16x32_bf16(af[tm][2], b0, a, 0, 0, 0);
          acc[tm][tn] = a;
        }
      }
    }
#pragma unroll
    for (int tm = 0; tm < 4; ++tm) {
#pragma unroll
      for (int tn = 0; tn < 4; ++tn) {
#pragma unroll
        for (int r = 0; r < 4; ++r) {
          int m = m0 + wm * 64 + tm * 16 + quad * 4 + r;
          int n = n0 + wn * 64 + tn * 16 + l15;
          int b = m >> 10, t = m & 1023, h = n >> 6, f = n & 63;
          size_t idx = (((size_t)(b * 16 + h)) * 1024 + t) * 64 + f;
          if (zi == 0) {
            qf[idx] = acc[tm][tn][r];
          } else {
            ushort hu, mu, lu;
            split3(acc[tm][tn][r], hu, mu, lu);
            kh[idx] = hu; km[idx] = mu; kl[idx] = lu;
          }
        }
      }
    }
  } else {
    const ushort* wt = wT + (size_t)6 * (1u << 20);
    const ushort* bpb = wt + (size_t)(n0 + sr) * 1024 + q0 * 8;
    bf16x8 pah0 = *(const bf16x8*)(axh);
    bf16x8 pah1 = *(const bf16x8*)(axh + 8);
    bf16x8 pb0 = *(const bf16x8*)(bpb);
    bf16x8 pb1 = *(const bf16x8*)(bpb + 8);
    for (int k0 = 0; k0 < 1024; k0 += 32) {
      __syncthreads();
      {
        *(bf16x8*)&As[wb0] = pah0; *(bf16x8*)&As[wb1] = pah1;
        *(bf16x8*)&Bs[wb0] = pb0;  *(bf16x8*)&Bs[wb1] = pb1;
      }
      __syncthreads();
      if (k0 < 992) {
        const int ko = k0 + 32;
        pah0 = *(const bf16x8*)(axh + ko);
        pah1 = *(const bf16x8*)(axh + ko + 8);
        pb0 = *(const bf16x8*)(bpb + ko);
        pb1 = *(const bf16x8*)(bpb + ko + 8);
      }
      bf16x8 af[4];
#pragma unroll
      for (int tm = 0; tm < 4; ++tm)
        af[tm] = *(const bf16x8*)&As[FRAG_IDX(wm * 4 + tm, quad, l15)];
#pragma unroll
      for (int tn = 0; tn < 4; ++tn) {
        bf16x8 b0 = *(const bf16x8*)&Bs[FRAG_IDX(wn * 4 + tn, quad, l15)];
#pragma unroll
        for (int tm = 0; tm < 4; ++tm)
          acc[tm][tn] = __builtin_amdgcn_mfma_f32_16x16x32_bf16(af[tm], b0, acc[tm][tn], 0, 0, 0);
      }
    }
#pragma unroll
    for (int tm = 0; tm < 4; ++tm) {
#pragma unroll
      for (int tn = 0; tn < 4; ++tn) {
#pragma unroll
        for (int r = 0; r < 4; ++r) {
          int m = m0 + wm * 64 + tm * 16 + quad * 4 + r;
          int n = n0 + wn * 64 + tn * 16 + l15;
          int b = m >> 10, t = m & 1023, h = n >> 6, f = n & 63;
          vt[(((size_t)(b * 16 + h)) * 64 + f) * 1024 + t] = f2bf(acc[tm][tn][r]);
        }
      }
    }
  }
}

// ---------------------------------------------------------------------------
// Fallback (small workspace): proj with in-loop split3t.
// ---------------------------------------------------------------------------
__global__ __launch_bounds__(256) void proj_all_mfma(
    const float* __restrict__ x, const ushort* __restrict__ wT,
    float* __restrict__ qf, ushort* __restrict__ kh,
    ushort* __restrict__ km, ushort* __restrict__ kl,
    ushort* __restrict__ vt)
{
  const int zi = blockIdx.z;
  const int m0 = blockIdx.x * 128, n0 = blockIdx.y * 128;
  __shared__ ushort As[3 * 4096];
  __shared__ ushort Bs[3 * 4096];
  const int tid = threadIdx.x;
  const int wave = tid >> 6, lane = tid & 63, l15 = lane & 15, quad = lane >> 4;
  const int wm = wave >> 1, wn = wave & 1;
  const int sr = tid >> 1, q0 = (tid & 1) * 2;
  const int wb0 = FRAG_IDX(sr >> 4, q0, sr & 15);
  const int wb1 = FRAG_IDX(sr >> 4, q0 + 1, sr & 15);
  f32x4 acc[4][4] = {};

  const float* apx = x + (size_t)(m0 + sr) * 1024 + q0 * 8;
  float4 px0 = *(const float4*)(apx);
  float4 px1 = *(const float4*)(apx + 4);
  float4 px2 = *(const float4*)(apx + 8);
  float4 px3 = *(const float4*)(apx + 12);

  if (zi < 2) {
    const ushort* wt = wT + (size_t)zi * 3 * (1u << 20);
    const ushort* bpb = wt + (size_t)(n0 + sr) * 1024 + q0 * 8;
    bf16x8 pb0[3], pb1[3];
#pragma unroll
    for (int s = 0; s < 3; ++s) {
      const ushort* bp = bpb + ((size_t)s << 20);
      pb0[s] = *(const bf16x8*)(bp);
      pb1[s] = *(const bf16x8*)(bp + 8);
    }
    for (int k0 = 0; k0 < 1024; k0 += 32) {
      __syncthreads();
      {
        float xs[16];
        *(float4*)&xs[0]  = px0;
        *(float4*)&xs[4]  = px1;
        *(float4*)&xs[8]  = px2;
        *(float4*)&xs[12] = px3;
        bf16x8 h0, h1, m0v, m1v, l0, l1;
#pragma unroll
        for (int j = 0; j < 8; ++j) {
          ushort hu, mu, lu;
          split3t(xs[j], hu, mu, lu);
          h0[j] = (short)hu; m0v[j] = (short)mu; l0[j] = (short)lu;
          split3t(xs[j + 8], hu, mu, lu);
          h1[j] = (short)hu; m1v[j] = (short)mu; l1[j] = (short)lu;
        }
        *(bf16x8*)&As[wb0] = h0;          *(bf16x8*)&As[wb1] = h1;
        *(bf16x8*)&As[4096 + wb0] = m0v;  *(bf16x8*)&As[4096 + wb1] = m1v;
        *(bf16x8*)&As[8192 + wb0] = l0;   *(bf16x8*)&As[8192 + wb1] = l1;
#pragma unroll
        for (int s = 0; s < 3; ++s) {
          *(bf16x8*)&Bs[s * 4096 + wb0] = pb0[s];
          *(bf16x8*)&Bs[s * 4096 + wb1] = pb1[s];
        }
      }
      __syncthreads();
      if (k0 < 992) {
        const float* nx = apx + k0 + 32;
        px0 = *(const float4*)(nx);
        px1 = *(const float4*)(nx + 4);
        px2 = *(const float4*)(nx + 8);
        px3 = *(const float4*)(nx + 12);
#pragma unroll
        for (int s = 0; s < 3; ++s) {
          const ushort* bp = bpb + ((size_t)s << 20) + k0 + 32;
          pb0[s] = *(const bf16x8*)(bp);
          pb1[s] = *(const bf16x8*)(bp + 8);
        }
      }
      bf16x8 af[4][3];
#pragma unroll
      for (int tm = 0; tm < 4; ++tm)
#pragma unroll
        for (int s = 0; s < 3; ++s)
          af[tm][s] = *(const bf16x8*)&As[s * 4096 + FRAG_IDX(wm * 4 + tm, quad, l15)];
#pragma unroll
      for (int tn = 0; tn < 4; ++tn) {
        const int bi = FRAG_IDX(wn * 4 + tn, quad, l15);
        bf16x8 b0 = *(const bf16x8*)&Bs[bi];
        bf16x8 b1 = *(const bf16x8*)&Bs[4096 + bi];
        bf16x8 b2 = *(const bf16x8*)&Bs[8192 + bi];
#pragma unroll
        for (int tm = 0; tm < 4; ++tm) {
          f32x4 a = acc[tm][tn];
          a = __builtin_amdgcn_mfma_f32_16x16x32_bf16(af[tm][0], b0, a, 0, 0, 0);
          a = __builtin_amdgcn_mfma_f32_16x16x32_bf16(af[tm][0], b1, a, 0, 0, 0);
          a = __builtin_amdgcn_mfma_f32_16x16x32_bf16(af[tm][1], b0, a, 0, 0, 0);
          a = __builtin_amdgcn_mfma_f32_16x16x32_bf16(af[tm][0], b2, a, 0, 0, 0);
          a = __builtin_amdgcn_mfma_f32_16x16x32_bf16(af[tm][1], b1, a, 0, 0, 0);
          a = __builtin_amdgcn_mfma_f32_16x16x32_bf16(af[tm][2], b0, a, 0, 0, 0);
          acc[tm][tn] = a;
        }
      }
    }
#pragma unroll
    for (int tm = 0; tm < 4; ++tm) {
#pragma unroll
      for (int tn = 0; tn < 4; ++tn) {
#pragma unroll
        for (int r = 0; r < 4; ++r) {
          int m = m0 + wm * 64 + tm * 16 + quad * 4 + r;
          int n = n0 + wn * 64 + tn * 16 + l15;
          int b = m >> 10, t = m & 1023, h = n >> 6, f = n & 63;
          size_t idx = (((size_t)(b * 16 + h)) * 1024 + t) * 64 + f;
          if (zi == 0) {
            qf[idx] = acc[tm][tn][r];
          } else {
            ushort hu, mu, lu;
            split3(acc[tm][tn][r], hu, mu, lu);
            kh[idx] = hu; km[idx] = mu; kl[idx] = lu;
          }
        }
      }
    }
  } else {
    const ushort* wt = wT + (size_t)6 * (1u << 20);
    const ushort* bpb = wt + (size_t)(n0 + sr) * 1024 + q0 * 8;
    bf16x8 pb0 = *(const bf16x8*)(bpb);
    bf16x8 pb1 = *(const bf16x8*)(bpb + 8);
    for (int k0 = 0; k0 < 1024; k0 += 32) {
      __syncthreads();
      {
        float xs[16];
        *(float4*)&xs[0]  = px0;
        *(float4*)&xs[4]  = px1;
        *(float4*)&xs[8]  = px2;
        *(float4*)&xs[12] = px3;
        bf16x8 h0, h1;
#pragma unroll
        for (int j = 0; j < 8; ++j) {
          h0[j] = (short)f2bf(xs[j]);
          h1[j] = (short)f2bf(xs[j + 8]);
        }
        *(bf16x8*)&As[wb0] = h0; *(bf16x8*)&As[wb1] = h1;
        *(bf16x8*)&Bs[wb0] = pb0; *(bf16x8*)&Bs[wb1] = pb1;
      }
      __syncthreads();
      if (k0 < 992) {
        const float* nx = apx + k0 + 32;
        px0 = *(const float4*)(nx);
        px1 = *(const float4*)(nx + 4);
        px2 = *(const float4*)(nx + 8);
        px3 = *(const float4*)(nx + 12);
        pb0 = *(const bf16x8*)(bpb + k0 + 32);
        pb1 = *(const bf16x8*)(bpb + k0 + 40);
      }
      bf16x8 af[4];
#pragma unroll
      for (int tm = 0; tm < 4; ++tm)
        af[tm] = *(const bf16x8*)&As[FRAG_IDX(wm * 4 + tm, quad, l15)];
#pragma unroll
      for (int tn = 0; tn < 4; ++tn) {
        bf16x8 b0 = *(const bf16x8*)&Bs[FRAG_IDX(wn * 4 + tn, quad, l15)];
#pragma unroll
        for (int tm = 0; tm < 4; ++tm)
          acc[tm][tn] = __builtin_amdgcn_mfma_f32_16x16x32_bf16(af[tm], b0, acc[tm][tn], 0, 0, 0);
      }
    }
#pragma unroll
    for (int tm = 0; tm < 4; ++tm) {
#pragma unroll
      for (int tn = 0; tn < 4; ++tn) {
#pragma unroll
        for (int r = 0; r < 4; ++r) {
          int m = m0 + wm * 64 + tm * 16 + quad * 4 + r;
          int n = n0 + wn * 64 + tn * 16 + l15;
          int b = m >> 10, t = m & 1023, h = n >> 6, f = n & 63;
          vt[(((size_t)(b * 16 + h)) * 64 + f) * 1024 + t] = f2bf(acc[tm][tn][r]);
        }
      }
    }
  }
}

// ---------------------------------------------------------------------------
// Flash attention (unchanged).
// ---------------------------------------------------------------------------
__global__ __launch_bounds__(512) void attn_mfma(
    const float* __restrict__ qf, const ushort* __restrict__ kh,
    const ushort* __restrict__ km, const ushort* __restrict__ kl,
    const ushort* __restrict__ vt, ushort* __restrict__ zh, ushort* __restrict__ zl)
{
  __shared__ ushort Ks[3][64][68];
  __shared__ ushort Vs[64][68];
  __shared__ ushort Pl[8][16][68];

  const int tid = threadIdx.x;
  const int wave = tid >> 6, lane = tid & 63;
  const int l15 = lane & 15, quad = lane >> 4;
  const int bh = blockIdx.y;
  const int qbase = blockIdx.x * 128;

  bf16x8 aqh[2], aqm[2], aql[2];
  {
    const int qrow = qbase + wave * 16 + l15;
    const float* qp = qf + ((size_t)bh * Tc + qrow) * Fc;
#pragma unroll
    for (int ks = 0; ks < 2; ++ks) {
      int f0 = ks * 32 + quad * 8;
      float4 x0 = *(const float4*)(qp + f0);
      float4 x1 = *(const float4*)(qp + f0 + 4);
      float xs[8] = {x0.x, x0.y, x0.z, x0.w, x1.x, x1.y, x1.z, x1.w};
#pragma unroll
      for (int j = 0; j < 8; ++j) {
        ushort hu, mu, lu;
        split3(xs[j], hu, mu, lu);
        aqh[ks][j] = (short)hu; aqm[ks][j] = (short)mu; aql[ks][j] = (short)lu;
      }
    }
  }

  f32x4 o[4] = {{0,0,0,0},{0,0,0,0},{0,0,0,0},{0,0,0,0}};
  float m_run[4], l_run[4];
#pragma unroll
  for (int r = 0; r < 4; ++r) { m_run[r] = -1e30f; l_run[r] = 0.f; }

  const int srow = tid >> 3, sc8 = tid & 7;
  const size_t kbase = (size_t)bh * Tc * Fc;
  const size_t vbase = (size_t)bh * Fc * Tc;
  const ushort* kp0 = kh + kbase + (size_t)srow * Fc + sc8 * 8;
  const ushort* kp1 = km + kbase + (size_t)srow * Fc + sc8 * 8;
  const ushort* kp2 = kl + kbase + (size_t)srow * Fc + sc8 * 8;
  const ushort* vp  = vt + vbase + (size_t)srow * Tc + sc8 * 8;

  for (int kt = 0; kt < Tc; kt += 64) {
    __syncthreads();
    {
      const size_t ko = (size_t)kt * Fc;
      *(bf16x8*)&Ks[0][srow][sc8 * 8] = *(const bf16x8*)(kp0 + ko);
      *(bf16x8*)&Ks[1][srow][sc8 * 8] = *(const bf16x8*)(kp1 + ko);
      *(bf16x8*)&Ks[2][srow][sc8 * 8] = *(const bf16x8*)(kp2 + ko);
      *(bf16x8*)&Vs[srow][sc8 * 8]    = *(const bf16x8*)(vp + kt);
    }
    __syncthreads();

    f32x4 sacc[4] = {{0,0,0,0},{0,0,0,0},{0,0,0,0},{0,0,0,0}};
#pragma unroll
    for (int nt = 0; nt < 4; ++nt) {
      int key = nt * 16 + l15;
#pragma unroll
      for (int ks = 0; ks < 2; ++ks) {
        int f0 = ks * 32 + quad * 8;
        bf16x8 bh_ = *(const bf16x8*)&Ks[0][key][f0];
        bf16x8 bm_ = *(const bf16x8*)&Ks[1][key][f0];
        bf16x8 bl_ = *(const bf16x8*)&Ks[2][key][f0];
        sacc[nt] = __builtin_amdgcn_mfma_f32_16x16x32_bf16(aqh[ks], bh_, sacc[nt], 0, 0, 0);
        sacc[nt] = __builtin_amdgcn_mfma_f32_16x16x32_bf16(aqh[ks], bm_, sacc[nt], 0, 0, 0);
        sacc[nt] = __builtin_amdgcn_mfma_f32_16x16x32_bf16(aqm[ks], bh_, sacc[nt], 0, 0, 0);
        sacc[nt] = __builtin_amdgcn_mfma_f32_16x16x32_bf16(aqh[ks], bl_, sacc[nt], 0, 0, 0);
        sacc[nt] = __builtin_amdgcn_mfma_f32_16x16x32_bf16(aqm[ks], bm_, sacc[nt], 0, 0, 0);
        sacc[nt] = __builtin_amdgcn_mfma_f32_16x16x32_bf16(aql[ks], bh_, sacc[nt], 0, 0, 0);
      }
    }

    const int rowg0 = qbase + wave * 16 + quad * 4;
    float mx[4];
#pragma unroll
    for (int r = 0; r < 4; ++r) mx[r] = -1e30f;
#pragma unroll
    for (int nt = 0; nt < 4; ++nt) {
      int key = kt + nt * 16 + l15;
#pragma unroll
      for (int r = 0; r < 4; ++r) {
        float s = sacc[nt][r];
        if (key > rowg0 + r) s *= -1.0e9f + 1.0f;
        s *= 0.125f;
        sacc[nt][r] = s;
        mx[r] = fmaxf(mx[r], s);
      }
    }
#pragma unroll
    for (int r = 0; r < 4; ++r)
#pragma unroll
      for (int d = 1; d < 16; d <<= 1) mx[r] = fmaxf(mx[r], __shfl_xor(mx[r], d));

    float corr[4], ps[4];
#pragma unroll
    for (int r = 0; r < 4; ++r) {
      float m2 = fmaxf(m_run[r], mx[r]);
      corr[r] = __expf(m_run[r] - m2);
      m_run[r] = m2;
      ps[r] = 0.f;
    }
#pragma unroll
    for (int nt = 0; nt < 4; ++nt) {
#pragma unroll
      for (int r = 0; r < 4; ++r) {
        float p = __expf(sacc[nt][r] - m_run[r]);
        ps[r] += p;
        Pl[wave][quad * 4 + r][nt * 16 + l15] = f2bf(p);
      }
    }
#pragma unroll
    for (int r = 0; r < 4; ++r) {
#pragma unroll
      for (int d = 1; d < 16; d <<= 1) ps[r] += __shfl_xor(ps[r], d);
      l_run[r] = l_run[r] * corr[r] + ps[r];
#pragma unroll
      for (int ft = 0; ft < 4; ++ft) o[ft][r] *= corr[r];
    }

#pragma unroll
    for (int ks2 = 0; ks2 < 2; ++ks2) {
      bf16x8 pa = *(const bf16x8*)&Pl[wave][l15][ks2 * 32 + quad * 8];
#pragma unroll
      for (int ft = 0; ft < 4; ++ft) {
        bf16x8 vb = *(const bf16x8*)&Vs[ft * 16 + l15][ks2 * 32 + quad * 8];
        o[ft] = __builtin_amdgcn_mfma_f32_16x16x32_bf16(pa, vb, o[ft], 0, 0, 0);
      }
    }
  }

  const int b = bh >> 4, h = bh & 15;
#pragma unroll
  for (int r = 0; r < 4; ++r) {
    float inv = 1.f / l_run[r];
    int row = qbase + wave * 16 + quad * 4 + r;
    size_t base = ((size_t)(b * Tc + row)) * Ec + h * Fc;
#pragma unroll
    for (int ft = 0; ft < 4; ++ft) {
      ushort hu, lu;
      split2(o[ft][r] * inv, hu, lu);
      zh[base + ft * 16 + l15] = hu;
      zl[base + ft * 16 + l15] = lu;
    }
  }
}

// ---------------------------------------------------------------------------
// fr GEMM: tile 128x64 (round-5 proven: sr/q0 staging + reg-prefetch).
// ---------------------------------------------------------------------------
__global__ __launch_bounds__(256) void gemm_fr_mfma(
    const ushort* __restrict__ zh, const ushort* __restrict__ zl,
    const ushort* __restrict__ frT, const float* __restrict__ x,
    float* __restrict__ s1, float2* __restrict__ part)
{
  const int bb = blockIdx.z;
  const int m0 = blockIdx.x * 128, n0 = blockIdx.y * 64;
  __shared__ ushort Ah[4096], Al[4096], Bh[2048], Bl[2048];
  __shared__ float2 red[256];
  const int tid = threadIdx.x;
  const int wave = tid >> 6, lane = tid & 63, l15 = lane & 15, quad = lane >> 4;
  const int wm = wave >> 1, wn = wave & 1;
  const int sr = tid >> 1, q0 = (tid & 1) * 2;
  const int wb0 = FRAG_IDX(sr >> 4, q0, sr & 15);
  const int wb1 = FRAG_IDX(sr >> 4, q0 + 1, sr & 15);
  const int sr2 = tid >> 2, qb = tid & 3;
  const int wbB = FRAG_IDX(sr2 >> 4, qb, sr2 & 15);
  f32x4 acc[4][2] = {};
  const size_t abase = ((size_t)bb * 1024 + m0 + sr) * 1024 + q0 * 8;
  const size_t bbase = ((size_t)bb * 1024 + n0 + sr2) * 1024 + qb * 8;
  const ushort* blp = frT + (4u << 20);
  bf16x8 pAh0 = *(const bf16x8*)(zh + abase);
  bf16x8 pAh1 = *(const bf16x8*)(zh + abase + 8);
  bf16x8 pAl0 = *(const bf16x8*)(zl + abase);
  bf16x8 pAl1 = *(const bf16x8*)(zl + abase + 8);
  bf16x8 pBh  = *(const bf16x8*)(frT + bbase);
  bf16x8 pBl  = *(const bf16x8*)(blp + bbase);
  for (int k0 = 0; k0 < 1024; k0 += 32) {
    __syncthreads();
    {
      *(bf16x8*)&Ah[wb0] = pAh0;
      *(bf16x8*)&Ah[wb1] = pAh1;
      *(bf16x8*)&Al[wb0] = pAl0;
      *(bf16x8*)&Al[wb1] = pAl1;
      *(bf16x8*)&Bh[wbB] = pBh;
      *(bf16x8*)&Bl[wbB] = pBl;
    }
    __syncthreads();
    if (k0 < 992) {
      pAh0 = *(const bf16x8*)(zh + abase + k0 + 32);
      pAh1 = *(const bf16x8*)(zh + abase + k0 + 40);
      pAl0 = *(const bf16x8*)(zl + abase + k0 + 32);
      pAl1 = *(const bf16x8*)(zl + abase + k0 + 40);
      pBh  = *(const bf16x8*)(frT + bbase + k0 + 32);
      pBl  = *(const bf16x8*)(blp + bbase + k0 + 32);
    }
    bf16x8 ah[4], al[4];
#pragma unroll
    for (int tm = 0; tm < 4; ++tm) {
      ah[tm] = *(const bf16x8*)&Ah[FRAG_IDX(wm * 4 + tm, quad, l15)];
      al[tm] = *(const bf16x8*)&Al[FRAG_IDX(wm * 4 + tm, quad, l15)];
    }
#pragma unroll
    for (int tn = 0; tn < 2; ++tn) {
      const int bi = FRAG_IDX(wn * 2 + tn, quad, l15);
      bf16x8 b0 = *(const bf16x8*)&Bh[bi];
      bf16x8 b1 = *(const bf16x8*)&Bl[bi];
#pragma unroll
      for (int tm = 0; tm < 4; ++tm) {
        f32x4 a = acc[tm][tn];
        a = __builtin_amdgcn_mfma_f32_16x16x32_bf16(ah[tm], b0, a, 0, 0, 0);
        a = __builtin_amdgcn_mfma_f32_16x16x32_bf16(ah[tm], b1, a, 0, 0, 0);
        a = __builtin_amdgcn_mfma_f32_16x16x32_bf16(al[tm], b0, a, 0, 0, 0);
        acc[tm][tn] = a;
      }
    }
  }
  float sum = 0.f, sq = 0.f;
#pragma unroll
  for (int tm = 0; tm < 4; ++tm) {
#pragma unroll
    for (int tn = 0; tn < 2; ++tn) {
#pragma unroll
      for (int r = 0; r < 4; ++r) {
        int m = m0 + wm * 64 + tm * 16 + quad * 4 + r;
        int n = n0 + wn * 32 + tn * 16 + l15;
        size_t idx = ((size_t)bb * 1024 + m) * 1024 + n;
        float o = x[idx] + acc[tm][tn][r];
        s1[idx] = o;
        sum += o; sq += o * o;
      }
    }
  }
  red[tid] = make_float2(sum, sq);
  __syncthreads();
  for (int s = 128; s > 0; s >>= 1) {
    if (tid < s) { red[tid].x += red[tid + s].x; red[tid].y += red[tid + s].y; }
    __syncthreads();
  }
  if (tid == 0) part[bb * 128 + blockIdx.x * 16 + blockIdx.y] = red[0];
}

// ---------------------------------------------------------------------------
// ff GEMM: tile 128x64 (round-5 proven staging).
// ---------------------------------------------------------------------------
__global__ __launch_bounds__(256) void gemm_ff_mfma(
    const ushort* __restrict__ z1h, const ushort* __restrict__ z1l,
    const ushort* __restrict__ fwh, const ushort* __restrict__ fwl,
    const float* __restrict__ ffb, float* __restrict__ s2,
    float2* __restrict__ part)
{
  const int m0 = blockIdx.x * 128, n0 = blockIdx.y * 64;
  __shared__ ushort Ah[4096], Al[4096], Bh[2048], Bl[2048];
  __shared__ float2 red[256];
  const int tid = threadIdx.x;
  const int wave = tid >> 6, lane = tid & 63, l15 = lane & 15, quad = lane >> 4;
  const int wm = wave >> 1, wn = wave & 1;
  const int sr = tid >> 1, q0 = (tid & 1) * 2;
  const int wb0 = FRAG_IDX(sr >> 4, q0, sr & 15);
  const int wb1 = FRAG_IDX(sr >> 4, q0 + 1, sr & 15);
  const int sr2 = tid >> 2, qb = tid & 3;
  const int wbB = FRAG_IDX(sr2 >> 4, qb, sr2 & 15);
  f32x4 acc[4][2] = {};
  const size_t abase = (size_t)(m0 + sr) * 1024 + q0 * 8;
  const size_t bbase = (size_t)(n0 + sr2) * 1024 + qb * 8;
  bf16x8 pAh0 = *(const bf16x8*)(z1h + abase);
  bf16x8 pAh1 = *(const bf16x8*)(z1h + abase + 8);
  bf16x8 pAl0 = *(const bf16x8*)(z1l + abase);
  bf16x8 pAl1 = *(const bf16x8*)(z1l + abase + 8);
  bf16x8 pBh  = *(const bf16x8*)(fwh + bbase);
  bf16x8 pBl  = *(const bf16x8*)(fwl + bbase);
  for (int k0 = 0; k0 < 1024; k0 += 32) {
    __syncthreads();
    {
      *(bf16x8*)&Ah[wb0] = pAh0;
      *(bf16x8*)&Ah[wb1] = pAh1;
      *(bf16x8*)&Al[wb0] = pAl0;
      *(bf16x8*)&Al[wb1] = pAl1;
      *(bf16x8*)&Bh[wbB] = pBh;
      *(bf16x8*)&Bl[wbB] = pBl;
    }
    __syncthreads();
    if (k0 < 992) {
      pAh0 = *(const bf16x8*)(z1h + abase + k0 + 32);
      pAh1 = *(const bf16x8*)(z1h + abase + k0 + 40);
      pAl0 = *(const bf16x8*)(z1l + abase + k0 + 32);
      pAl1 = *(const bf16x8*)(z1l + abase + k0 + 40);
      pBh  = *(const bf16x8*)(fwh + bbase + k0 + 32);
      pBl  = *(const bf16x8*)(fwl + bbase + k0 + 32);
    }
    bf16x8 ah[4], al[4];
#pragma unroll
    for (int tm = 0; tm < 4; ++tm) {
      ah[tm] = *(const bf16x8*)&Ah[FRAG_IDX(wm * 4 + tm, quad, l15)];
      al[tm] = *(const bf16x8*)&Al[FRAG_IDX(wm * 4 + tm, quad, l15)];
    }
#pragma unroll
    for (int tn = 0; tn < 2; ++tn) {
      const int bi = FRAG_IDX(wn * 2 + tn, quad, l15);
      bf16x8 b0 = *(const bf16x8*)&Bh[bi];
      bf16x8 b1 = *(const bf16x8*)&Bl[bi];
#pragma unroll
      for (int tm = 0; tm < 4; ++tm) {
        f32x4 a = acc[tm][tn];
        a = __builtin_amdgcn_mfma_f32_16x16x32_bf16(ah[tm], b0, a, 0, 0, 0);
        a = __builtin_amdgcn_mfma_f32_16x16x32_bf16(ah[tm], b1, a, 0, 0, 0);
        a = __builtin_amdgcn_mfma_f32_16x16x32_bf16(al[tm], b0, a, 0, 0, 0);
        acc[tm][tn] = a;
      }
    }
  }
  float sum = 0.f, sq = 0.f;
#pragma unroll
  for (int tm = 0; tm < 4; ++tm) {
#pragma unroll
    for (int tn = 0; tn < 2; ++tn) {
#pragma unroll
      for (int r = 0; r < 4; ++r) {
        int m = m0 + wm * 64 + tm * 16 + quad * 4 + r;
        int n = n0 + wn * 32 + tn * 16 + l15;
        size_t idx = (size_t)m * 1024 + n;
        float z1v = bf2f(z1h[idx]) + bf2f(z1l[idx]);
        float o = z1v + fmaxf(acc[tm][tn][r] + ffb[n], 0.f);
        s2[idx] = o;
        sum += o; sq += o * o;
      }
    }
  }
  red[tid] = make_float2(sum, sq);
  __syncthreads();
  for (int s = 128; s > 0; s >>= 1) {
    if (tid < s) { red[tid].x += red[tid + s].x; red[tid].y += red[tid + s].y; }
    __syncthreads();
  }
  if (tid == 0) part[blockIdx.x * 16 + blockIdx.y] = red[0];
}

__global__ __launch_bounds__(256) void ln_stats(
    const float2* __restrict__ part, float2* __restrict__ stats, int npart)
{
  __shared__ double sd[256], sq[256];
  const int tid = threadIdx.x;
  double as = 0.0, aq = 0.0;
  for (int i = tid; i < npart; i += 256) {
    float2 p = part[blockIdx.x * npart + i];
    as += (double)p.x; aq += (double)p.y;
  }
  sd[tid] = as; sq[tid] = aq;
  __syncthreads();
  for (int s = 128; s > 0; s >>= 1) {
    if (tid < s) { sd[tid] += sd[tid + s]; sq[tid] += sq[tid + s]; }
    __syncthreads();
  }
  if (tid == 0) {
    const double n = (double)Tc * Ec;
    double mean = sd[0] / n;
    double var = sq[0] / n - mean * mean;
    if (var < 0.0) var = 0.0;
    double rs = 1.0 / sqrt(var + 1e-5);
    stats[blockIdx.x] = make_float2((float)mean, (float)rs);
  }
}

// ln_norm -> split2 pair; blocks >= 4096 instead split2 ffw (folded launch).
__global__ __launch_bounds__(256) void ln_norm_split(
    const float* __restrict__ s, const float2* __restrict__ stats,
    const float* __restrict__ w, const float* __restrict__ bias,
    ushort* __restrict__ oh, ushort* __restrict__ ol,
    const float* __restrict__ ffw, ushort* __restrict__ fwh, ushort* __restrict__ fwl)
{
  if (blockIdx.x >= 4096) {
    int i = (blockIdx.x - 4096) * 256 + threadIdx.x;
#pragma unroll
    for (int j = 0; j < 4; ++j) {
      int idx = i * 4 + j;
      float4 v = ((const float4*)ffw)[idx];
      ushort4 h, l;
      split2(v.x, h.x, l.x); split2(v.y, h.y, l.y);
      split2(v.z, h.z, l.z); split2(v.w, h.w, l.w);
      ((ushort4*)fwh)[idx] = h; ((ushort4*)fwl)[idx] = l;
    }
    return;
  }
  int i = blockIdx.x * 256 + threadIdx.x;
  int b = i >> 18;
  int te4 = i & ((1 << 18) - 1);
  float2 st = stats[b];
  float4 sv = ((const float4*)s)[i];
  float4 wv = ((const float4*)w)[te4];
  float4 bv = ((const float4*)bias)[te4];
  float4 o;
  o.x = (sv.x - st.x) * st.y * wv.x + bv.x;
  o.y = (sv.y - st.x) * st.y * wv.y + bv.y;
  o.z = (sv.z - st.x) * st.y * wv.z + bv.z;
  o.w = (sv.w - st.x) * st.y * wv.w + bv.w;
  ushort4 h, l;
  split2(o.x, h.x, l.x); split2(o.y, h.y, l.y);
  split2(o.z, h.z, l.z); split2(o.w, h.w, l.w);
  ((ushort4*)oh)[i] = h; ((ushort4*)ol)[i] = l;
}

__global__ __launch_bounds__(256) void ln_norm(
    const float* __restrict__ s, const float2* __restrict__ stats,
    const float* __restrict__ w, const float* __restrict__ bias,
    float* __restrict__ out)
{
  int i = blockIdx.x * 256 + threadIdx.x;
  if (i >= (Bc * Tc * Ec) / 4) return;
  int b = i >> 18;
  int te4 = i & ((1 << 18) - 1);
  float2 st = stats[b];
  float4 sv = ((const float4*)s)[i];
  float4 wv = ((const float4*)w)[te4];
  float4 bv = ((const float4*)bias)[te4];
  float4 o;
  o.x = (sv.x - st.x) * st.y * wv.x + bv.x;
  o.y = (sv.y - st.x) * st.y * wv.y + bv.y;
  o.z = (sv.z - st.x) * st.y * wv.z + bv.z;
  o.w = (sv.w - st.x) * st.y * wv.w + bv.w;
  ((float4*)out)[i] = o;
}

// ---------------------------------------------------------------------------
extern "C" void kernel_launch(void* const* d_in, const int* in_sizes, int n_in,
                              void* d_out, int out_size, void* d_ws, size_t ws_size,
                              hipStream_t stream)
{
  const float* x    = (const float*)d_in[0];
  const float* qw   = (const float*)d_in[1];
  const float* kw   = (const float*)d_in[2];
  const float* vw   = (const float*)d_in[3];
  const float* frw  = (const float*)d_in[4];
  const float* ffw  = (const float*)d_in[5];
  const float* ffb  = (const float*)d_in[6];
  const float* ln1w = (const float*)d_in[7];
  const float* ln1b = (const float*)d_in[8];
  const float* ln2w = (const float*)d_in[9];
  const float* ln2b = (const float*)d_in[10];
  float* out = (float*)d_out;
  char* W = (char*)d_ws;

  const size_t MB = 1ull << 20;
  float*  qf  = (float*)(W);
  ushort* kh  = (ushort*)(W + 16 * MB);
  ushort* km  = (ushort*)(W + 24 * MB);
  ushort* kl  = (ushort*)(W + 32 * MB);
  ushort* vt  = (ushort*)(W + 40 * MB);
  ushort* wT  = (ushort*)(W + 48 * MB);
  ushort* zh  = (ushort*)(W + 48 * MB);
  ushort* zl  = (ushort*)(W + 56 * MB);
  ushort* frT = (ushort*)(W + 16 * MB);
  float*  s1  = (float*)(W);
  ushort* z1h = (ushort*)(W + 16 * MB);
  ushort* z1l = (ushort*)(W + 24 * MB);
  ushort* fwh = (ushort*)(W + 48 * MB);
  ushort* fwl = (ushort*)(W + 50 * MB);
  float*  s2  = (float*)(W + 32 * MB);
  float2* part1  = (float2*)(W + 64 * MB);
  float2* part2  = part1 + 1024;
  float2* stats1 = part2 + 1024;
  float2* stats2 = stats1 + 4;
  // x pre-split planes (only used when workspace permits)
  ushort* xh = (ushort*)(W + 65 * MB);
  ushort* xm = (ushort*)(W + 73 * MB);
  ushort* xl = (ushort*)(W + 81 * MB);
  const bool big_ws = ws_size >= 90 * MB;

  if (big_ws) {
    // z<3: weight transpose+split; z>=3: x_split (8 z-slices x 256 blocks)
    prep_all<<<dim3(16, 16, 11), 256, 0, stream>>>(qw, kw, vw, wT, x, xh, xm, xl);
    proj_all_ps<<<dim3(32, 8, 3), 256, 0, stream>>>(xh, xm, xl, wT, qf, kh, km, kl, vt);
  } else {
    prep_all<<<dim3(16, 16, 3), 256, 0, stream>>>(qw, kw, vw, wT, x, xh, xm, xl);
    proj_all_mfma<<<dim3(32, 8, 3), 256, 0, stream>>>(x, wT, qf, kh, km, kl, vt);
  }
  attn_mfma<<<dim3(8, 64), 512, 0, stream>>>(qf, kh, km, kl, vt, zh, zl);
  transp_frw<<<dim3(16, 16, 4), 256, 0, stream>>>(frw, frT);
  gemm_fr_mfma<<<dim3(8, 16, 4), 256, 0, stream>>>(zh, zl, frT, x, s1, part1);
  ln_stats<<<dim3(4), 256, 0, stream>>>(part1, stats1, 128);
  ln_norm_split<<<dim3(4352), 256, 0, stream>>>(s1, stats1, ln1w, ln1b, z1h, z1l,
                                                ffw, fwh, fwl);
  gemm_ff_mfma<<<dim3(32, 16), 256, 0, stream>>>(z1h, z1l, fwh, fwl, ffb, s2, part2);
  ln_stats<<<dim3(4), 256, 0, stream>>>(part2, stats2, 128);
  ln_norm<<<dim3(4096), 256, 0, stream>>>(s2, stats2, ln2w, ln2b, out);
}

// Round 8
// 400.597 us; speedup vs baseline: 1.1276x; 1.0349x over previous
//
#include <hip/hip_runtime.h>
#include <math.h>

constexpr int Bc = 4, Tc = 1024, Ec = 1024, Hc = 16, Fc = 64;

typedef __attribute__((ext_vector_type(8))) short bf16x8;
typedef __attribute__((ext_vector_type(4))) float f32x4;

__device__ __forceinline__ ushort f2bf(float x) {
  union { float f; unsigned u; } v; v.f = x;
  unsigned r = v.u + 0x7fffu + ((v.u >> 16) & 1u);
  return (ushort)(r >> 16);
}
__device__ __forceinline__ float bf2f(ushort h) {
  union { float f; unsigned u; } v; v.u = ((unsigned)h) << 16; return v.f;
}
__device__ __forceinline__ void split3(float x, ushort& h, ushort& m, ushort& l) {
  h = f2bf(x);
  float r1 = x - bf2f(h);
  m = f2bf(r1);
  float r2 = r1 - bf2f(m);
  l = f2bf(r2);
}
__device__ __forceinline__ void split2(float x, ushort& h, ushort& l) {
  h = f2bf(x);
  l = f2bf(x - bf2f(h));
}
// Truncation split3 (~8 VALU ops): one-sided residual < 2^-22 rel.
__device__ __forceinline__ void split3t(float x, ushort& h, ushort& m, ushort& l) {
  union { float f; unsigned u; } v; v.f = x;
  h = (ushort)(v.u >> 16);
  union { float f; unsigned u; } hf; hf.u = v.u & 0xffff0000u;
  float r1 = x - hf.f;
  union { float f; unsigned u; } v1; v1.f = r1;
  m = (ushort)(v1.u >> 16);
  union { float f; unsigned u; } mf; mf.u = v1.u & 0xffff0000u;
  float r2 = r1 - mf.f;
  union { float f; unsigned u; } v2; v2.f = r2;
  l = (ushort)(v2.u >> 16);
}

// Fragment-major LDS cell: [tile][quad(0..3)][lane(0..15)][8 ushorts]
// NOTE (rounds 2+6, measured): do NOT replace the sr/q0 scatter staging with
// wave-linear "conflict-free" chunks. The 7.34M LDS write conflicts are
// hidden under multi-wave overlap; the wave-linear variant doubles distinct
// cache lines per thread (12 vs 6) and regresses proj by ~20%.
#define FRAG_IDX(tile, quad, l) (((((tile) * 4) + (quad)) * 16 + (l)) * 8)

// ---------------------------------------------------------------------------
// Merged prep: z<3 = transpose+split projection weights; z>=3 = x_split.
// ---------------------------------------------------------------------------
__global__ __launch_bounds__(256) void prep_all(
    const float* __restrict__ qw, const float* __restrict__ kw,
    const float* __restrict__ vw, ushort* __restrict__ wT,
    const float* __restrict__ x, ushort* __restrict__ xh,
    ushort* __restrict__ xm, ushort* __restrict__ xl)
{
  const int zi = blockIdx.z;
  const int tid = threadIdx.x;
  if (zi >= 3) {
    // x_split: one-time split3t of x into three bf16 planes.
    const int bid = (zi - 3) * 256 + blockIdx.y * 16 + blockIdx.x;
    const int i = bid * 256 + tid;  // 8 elements per thread
    const float4 a = ((const float4*)x)[i * 2];
    const float4 b = ((const float4*)x)[i * 2 + 1];
    const float xs[8] = {a.x, a.y, a.z, a.w, b.x, b.y, b.z, b.w};
    bf16x8 h, m, l;
#pragma unroll
    for (int j = 0; j < 8; ++j) {
      ushort hu, mu, lu;
      split3t(xs[j], hu, mu, lu);
      h[j] = (short)hu; m[j] = (short)mu; l[j] = (short)lu;
    }
    ((bf16x8*)xh)[i] = h;
    ((bf16x8*)xm)[i] = m;
    ((bf16x8*)xl)[i] = l;
    return;
  }
  const float* src = (zi == 0) ? qw : (zi == 1) ? kw : vw;
  ushort* dst = wT + (size_t)(zi * 3) * (1u << 20);
  const int ns = (zi == 2) ? 1 : 3;
  const int h = blockIdx.y, e0 = blockIdx.x * 64;
  __shared__ float T[64][68];
  {
    const int er = tid >> 4, fr = (tid & 15) * 4;
#pragma unroll
    for (int i = 0; i < 4; ++i) {
      const float4 v = *(const float4*)&src[((size_t)(h * 1024 + e0 + er + i * 16)) * 64 + fr];
      *(float4*)&T[er + i * 16][fr] = v;
    }
  }
  __syncthreads();
  const int f = tid >> 2, eo = (tid & 3) * 16;
  ushort hs[16], ms[16], ls[16];
#pragma unroll
  for (int j = 0; j < 16; ++j) split3(T[eo + j][f], hs[j], ms[j], ls[j]);
  const size_t nbase = (size_t)(h * 64 + f) * 1024 + e0 + eo;
  bf16x8 v0, v1;
#pragma unroll
  for (int j = 0; j < 8; ++j) { v0[j] = (short)hs[j]; v1[j] = (short)hs[j + 8]; }
  *(bf16x8*)&dst[nbase] = v0; *(bf16x8*)&dst[nbase + 8] = v1;
  if (ns == 3) {
#pragma unroll
    for (int j = 0; j < 8; ++j) { v0[j] = (short)ms[j]; v1[j] = (short)ms[j + 8]; }
    *(bf16x8*)&dst[(1u << 20) + nbase] = v0; *(bf16x8*)&dst[(1u << 20) + nbase + 8] = v1;
#pragma unroll
    for (int j = 0; j < 8; ++j) { v0[j] = (short)ls[j]; v1[j] = (short)ls[j + 8]; }
    *(bf16x8*)&dst[(2u << 20) + nbase] = v0; *(bf16x8*)&dst[(2u << 20) + nbase + 8] = v1;
  }
}

// ---------------------------------------------------------------------------
// Pre-transpose + split2 fr weights.
// ---------------------------------------------------------------------------
__global__ __launch_bounds__(256) void transp_frw(
    const float* __restrict__ frw, ushort* __restrict__ frT)
{
  const int bb = blockIdx.z;
  const int e0 = blockIdx.x * 64, d0 = blockIdx.y * 64;
  __shared__ float T[64][68];
  const int tid = threadIdx.x;
  {
    const int er = tid >> 4, dr = (tid & 15) * 4;
#pragma unroll
    for (int i = 0; i < 4; ++i) {
      const float4 v = *(const float4*)&frw[((size_t)bb * 1024 + e0 + er + i * 16) * 1024 + d0 + dr];
      *(float4*)&T[er + i * 16][dr] = v;
    }
  }
  __syncthreads();
  const int d = tid >> 2, eo = (tid & 3) * 16;
  ushort hs[16], ls[16];
#pragma unroll
  for (int j = 0; j < 16; ++j) split2(T[eo + j][d], hs[j], ls[j]);
  const size_t nbase = ((size_t)bb * 1024 + d0 + d) * 1024 + e0 + eo;
  bf16x8 v0, v1;
#pragma unroll
  for (int j = 0; j < 8; ++j) { v0[j] = (short)hs[j]; v1[j] = (short)hs[j + 8]; }
  *(bf16x8*)&frT[nbase] = v0; *(bf16x8*)&frT[nbase + 8] = v1;
#pragma unroll
  for (int j = 0; j < 8; ++j) { v0[j] = (short)ls[j]; v1[j] = (short)ls[j + 8]; }
  *(bf16x8*)&frT[(4u << 20) + nbase] = v0; *(bf16x8*)&frT[(4u << 20) + nbase + 8] = v1;
}

// ---------------------------------------------------------------------------
// Projections from pre-split x planes (round-5 proven version).
// ---------------------------------------------------------------------------
__global__ __launch_bounds__(256) void proj_all_ps(
    const ushort* __restrict__ xh, const ushort* __restrict__ xm,
    const ushort* __restrict__ xl, const ushort* __restrict__ wT,
    float* __restrict__ qf, ushort* __restrict__ kh,
    ushort* __restrict__ km, ushort* __restrict__ kl,
    ushort* __restrict__ vt)
{
  const int zi = blockIdx.z;
  const int m0 = blockIdx.x * 128, n0 = blockIdx.y * 128;
  __shared__ ushort As[3 * 4096];
  __shared__ ushort Bs[3 * 4096];
  const int tid = threadIdx.x;
  const int wave = tid >> 6, lane = tid & 63, l15 = lane & 15, quad = lane >> 4;
  const int wm = wave >> 1, wn = wave & 1;
  const int sr = tid >> 1, q0 = (tid & 1) * 2;
  const int wb0 = FRAG_IDX(sr >> 4, q0, sr & 15);
  const int wb1 = FRAG_IDX(sr >> 4, q0 + 1, sr & 15);
  f32x4 acc[4][4] = {};

  const size_t arow = (size_t)(m0 + sr) * 1024 + q0 * 8;
  const ushort* axh = xh + arow;
  const ushort* axm = xm + arow;
  const ushort* axl = xl + arow;

  if (zi < 2) {
    const ushort* wt = wT + (size_t)zi * 3 * (1u << 20);
    const ushort* bpb = wt + (size_t)(n0 + sr) * 1024 + q0 * 8;
    // current-window fragments in registers
    bf16x8 pah0 = *(const bf16x8*)(axh);
    bf16x8 pah1 = *(const bf16x8*)(axh + 8);
    bf16x8 pam0 = *(const bf16x8*)(axm);
    bf16x8 pam1 = *(const bf16x8*)(axm + 8);
    bf16x8 pal0 = *(const bf16x8*)(axl);
    bf16x8 pal1 = *(const bf16x8*)(axl + 8);
    bf16x8 pb0[3], pb1[3];
#pragma unroll
    for (int s = 0; s < 3; ++s) {
      const ushort* bp = bpb + ((size_t)s << 20);
      pb0[s] = *(const bf16x8*)(bp);
      pb1[s] = *(const bf16x8*)(bp + 8);
    }
    for (int k0 = 0; k0 < 1024; k0 += 32) {
      __syncthreads();
      {
        *(bf16x8*)&As[wb0] = pah0;        *(bf16x8*)&As[wb1] = pah1;
        *(bf16x8*)&As[4096 + wb0] = pam0; *(bf16x8*)&As[4096 + wb1] = pam1;
        *(bf16x8*)&As[8192 + wb0] = pal0; *(bf16x8*)&As[8192 + wb1] = pal1;
#pragma unroll
        for (int s = 0; s < 3; ++s) {
          *(bf16x8*)&Bs[s * 4096 + wb0] = pb0[s];
          *(bf16x8*)&Bs[s * 4096 + wb1] = pb1[s];
        }
      }
      __syncthreads();
      // Prefetch next window in the compute phase (latency hidden under MFMA)
      if (k0 < 992) {
        const int ko = k0 + 32;
        pah0 = *(const bf16x8*)(axh + ko);
        pah1 = *(const bf16x8*)(axh + ko + 8);
        pam0 = *(const bf16x8*)(axm + ko);
        pam1 = *(const bf16x8*)(axm + ko + 8);
        pal0 = *(const bf16x8*)(axl + ko);
        pal1 = *(const bf16x8*)(axl + ko + 8);
#pragma unroll
        for (int s = 0; s < 3; ++s) {
          const ushort* bp = bpb + ((size_t)s << 20) + ko;
          pb0[s] = *(const bf16x8*)(bp);
          pb1[s] = *(const bf16x8*)(bp + 8);
        }
      }
      bf16x8 af[4][3];
#pragma unroll
      for (int tm = 0; tm < 4; ++tm)
#pragma unroll
        for (int s = 0; s < 3; ++s)
          af[tm][s] = *(const bf16x8*)&As[s * 4096 + FRAG_IDX(wm * 4 + tm, quad, l15)];
#pragma unroll
      for (int tn = 0; tn < 4; ++tn) {
        const int bi = FRAG_IDX(wn * 4 + tn, quad, l15);
        bf16x8 b0 = *(const bf16x8*)&Bs[bi];
        bf16x8 b1 = *(const bf16x8*)&Bs[4096 + bi];
        bf16x8 b2 = *(const bf16x8*)&Bs[8192 + bi];
#pragma unroll
        for (int tm = 0; tm < 4; ++tm) {
          f32x4 a = acc[tm][tn];
          a = __builtin_amdgcn_mfma_f32_16x16x32_bf16(af[tm][0], b0, a, 0, 0, 0);
          a = __builtin_amdgcn_mfma_f32_16x16x32_bf16(af[tm][0], b1, a, 0, 0, 0);
          a = __builtin_amdgcn_mfma_f32_16x16x32_bf16(af[tm][1], b0, a, 0, 0, 0);
          a = __builtin_amdgcn_mfma_f32_16x16x32_bf16(af[tm][0], b2, a, 0, 0, 0);
          a = __builtin_amdgcn_mfma_f32_16x16x32_bf16(af[tm][1], b1, a, 0, 0, 0);
          a = __builtin_amdgcn_mfma_f32_16x16x32_bf16(af[tm][2], b0, a, 0, 0, 0);
          acc[tm][tn] = a;
        }
      }
    }
#pragma unroll
    for (int tm = 0; tm < 4; ++tm) {
#pragma unroll
      for (int tn = 0; tn < 4; ++tn) {
#pragma unroll
        for (int r = 0; r < 4; ++r) {
          int m = m0 + wm * 64 + tm * 16 + quad * 4 + r;
          int n = n0 + wn * 64 + tn * 16 + l15;
          int b = m >> 10, t = m & 1023, h = n >> 6, f = n & 63;
          size_t idx = (((size_t)(b * 16 + h)) * 1024 + t) * 64 + f;
          if (zi == 0) {
            qf[idx] = acc[tm][tn][r];
          } else {
            ushort hu, mu, lu;
            split3(acc[tm][tn][r], hu, mu, lu);
            kh[idx] = hu; km[idx] = mu; kl[idx] = lu;
          }
        }
      }
    }
  } else {
    const ushort* wt = wT + (size_t)6 * (1u << 20);
    const ushort* bpb = wt + (size_t)(n0 + sr) * 1024 + q0 * 8;
    bf16x8 pah0 = *(const bf16x8*)(axh);
    bf16x8 pah1 = *(const bf16x8*)(axh + 8);
    bf16x8 pb0 = *(const bf16x8*)(bpb);
    bf16x8 pb1 = *(const bf16x8*)(bpb + 8);
    for (int k0 = 0; k0 < 1024; k0 += 32) {
      __syncthreads();
      {
        *(bf16x8*)&As[wb0] = pah0; *(bf16x8*)&As[wb1] = pah1;
        *(bf16x8*)&Bs[wb0] = pb0;  *(bf16x8*)&Bs[wb1] = pb1;
      }
      __syncthreads();
      if (k0 < 992) {
        const int ko = k0 + 32;
        pah0 = *(const bf16x8*)(axh + ko);
        pah1 = *(const bf16x8*)(axh + ko + 8);
        pb0 = *(const bf16x8*)(bpb + ko);
        pb1 = *(const bf16x8*)(bpb + ko + 8);
      }
      bf16x8 af[4];
#pragma unroll
      for (int tm = 0; tm < 4; ++tm)
        af[tm] = *(const bf16x8*)&As[FRAG_IDX(wm * 4 + tm, quad, l15)];
#pragma unroll
      for (int tn = 0; tn < 4; ++tn) {
        bf16x8 b0 = *(const bf16x8*)&Bs[FRAG_IDX(wn * 4 + tn, quad, l15)];
#pragma unroll
        for (int tm = 0; tm < 4; ++tm)
          acc[tm][tn] = __builtin_amdgcn_mfma_f32_16x16x32_bf16(af[tm], b0, acc[tm][tn], 0, 0, 0);
      }
    }
#pragma unroll
    for (int tm = 0; tm < 4; ++tm) {
#pragma unroll
      for (int tn = 0; tn < 4; ++tn) {
#pragma unroll
        for (int r = 0; r < 4; ++r) {
          int m = m0 + wm * 64 + tm * 16 + quad * 4 + r;
          int n = n0 + wn * 64 + tn * 16 + l15;
          int b = m >> 10, t = m & 1023, h = n >> 6, f = n & 63;
          vt[(((size_t)(b * 16 + h)) * 64 + f) * 1024 + t] = f2bf(acc[tm][tn][r]);
        }
      }
    }
  }
}

// ---------------------------------------------------------------------------
// Fallback (small workspace): proj with in-loop split3t.
// ---------------------------------------------------------------------------
__global__ __launch_bounds__(256) void proj_all_mfma(
    const float* __restrict__ x, const ushort* __restrict__ wT,
    float* __restrict__ qf, ushort* __restrict__ kh,
    ushort* __restrict__ km, ushort* __restrict__ kl,
    ushort* __restrict__ vt)
{
  const int zi = blockIdx.z;
  const int m0 = blockIdx.x * 128, n0 = blockIdx.y * 128;
  __shared__ ushort As[3 * 4096];
  __shared__ ushort Bs[3 * 4096];
  const int tid = threadIdx.x;
  const int wave = tid >> 6, lane = tid & 63, l15 = lane & 15, quad = lane >> 4;
  const int wm = wave >> 1, wn = wave & 1;
  const int sr = tid >> 1, q0 = (tid & 1) * 2;
  const int wb0 = FRAG_IDX(sr >> 4, q0, sr & 15);
  const int wb1 = FRAG_IDX(sr >> 4, q0 + 1, sr & 15);
  f32x4 acc[4][4] = {};

  const float* apx = x + (size_t)(m0 + sr) * 1024 + q0 * 8;
  float4 px0 = *(const float4*)(apx);
  float4 px1 = *(const float4*)(apx + 4);
  float4 px2 = *(const float4*)(apx + 8);
  float4 px3 = *(const float4*)(apx + 12);

  if (zi < 2) {
    const ushort* wt = wT + (size_t)zi * 3 * (1u << 20);
    const ushort* bpb = wt + (size_t)(n0 + sr) * 1024 + q0 * 8;
    bf16x8 pb0[3], pb1[3];
#pragma unroll
    for (int s = 0; s < 3; ++s) {
      const ushort* bp = bpb + ((size_t)s << 20);
      pb0[s] = *(const bf16x8*)(bp);
      pb1[s] = *(const bf16x8*)(bp + 8);
    }
    for (int k0 = 0; k0 < 1024; k0 += 32) {
      __syncthreads();
      {
        float xs[16];
        *(float4*)&xs[0]  = px0;
        *(float4*)&xs[4]  = px1;
        *(float4*)&xs[8]  = px2;
        *(float4*)&xs[12] = px3;
        bf16x8 h0, h1, m0v, m1v, l0, l1;
#pragma unroll
        for (int j = 0; j < 8; ++j) {
          ushort hu, mu, lu;
          split3t(xs[j], hu, mu, lu);
          h0[j] = (short)hu; m0v[j] = (short)mu; l0[j] = (short)lu;
          split3t(xs[j + 8], hu, mu, lu);
          h1[j] = (short)hu; m1v[j] = (short)mu; l1[j] = (short)lu;
        }
        *(bf16x8*)&As[wb0] = h0;          *(bf16x8*)&As[wb1] = h1;
        *(bf16x8*)&As[4096 + wb0] = m0v;  *(bf16x8*)&As[4096 + wb1] = m1v;
        *(bf16x8*)&As[8192 + wb0] = l0;   *(bf16x8*)&As[8192 + wb1] = l1;
#pragma unroll
        for (int s = 0; s < 3; ++s) {
          *(bf16x8*)&Bs[s * 4096 + wb0] = pb0[s];
          *(bf16x8*)&Bs[s * 4096 + wb1] = pb1[s];
        }
      }
      __syncthreads();
      if (k0 < 992) {
        const float* nx = apx + k0 + 32;
        px0 = *(const float4*)(nx);
        px1 = *(const float4*)(nx + 4);
        px2 = *(const float4*)(nx + 8);
        px3 = *(const float4*)(nx + 12);
#pragma unroll
        for (int s = 0; s < 3; ++s) {
          const ushort* bp = bpb + ((size_t)s << 20) + k0 + 32;
          pb0[s] = *(const bf16x8*)(bp);
          pb1[s] = *(const bf16x8*)(bp + 8);
        }
      }
      bf16x8 af[4][3];
#pragma unroll
      for (int tm = 0; tm < 4; ++tm)
#pragma unroll
        for (int s = 0; s < 3; ++s)
          af[tm][s] = *(const bf16x8*)&As[s * 4096 + FRAG_IDX(wm * 4 + tm, quad, l15)];
#pragma unroll
      for (int tn = 0; tn < 4; ++tn) {
        const int bi = FRAG_IDX(wn * 4 + tn, quad, l15);
        bf16x8 b0 = *(const bf16x8*)&Bs[bi];
        bf16x8 b1 = *(const bf16x8*)&Bs[4096 + bi];
        bf16x8 b2 = *(const bf16x8*)&Bs[8192 + bi];
#pragma unroll
        for (int tm = 0; tm < 4; ++tm) {
          f32x4 a = acc[tm][tn];
          a = __builtin_amdgcn_mfma_f32_16x16x32_bf16(af[tm][0], b0, a, 0, 0, 0);
          a = __builtin_amdgcn_mfma_f32_16x16x32_bf16(af[tm][0], b1, a, 0, 0, 0);
          a = __builtin_amdgcn_mfma_f32_16x16x32_bf16(af[tm][1], b0, a, 0, 0, 0);
          a = __builtin_amdgcn_mfma_f32_16x16x32_bf16(af[tm][0], b2, a, 0, 0, 0);
          a = __builtin_amdgcn_mfma_f32_16x16x32_bf16(af[tm][1], b1, a, 0, 0, 0);
          a = __builtin_amdgcn_mfma_f32_16x16x32_bf16(af[tm][2], b0, a, 0, 0, 0);
          acc[tm][tn] = a;
        }
      }
    }
#pragma unroll
    for (int tm = 0; tm < 4; ++tm) {
#pragma unroll
      for (int tn = 0; tn < 4; ++tn) {
#pragma unroll
        for (int r = 0; r < 4; ++r) {
          int m = m0 + wm * 64 + tm * 16 + quad * 4 + r;
          int n = n0 + wn * 64 + tn * 16 + l15;
          int b = m >> 10, t = m & 1023, h = n >> 6, f = n & 63;
          size_t idx = (((size_t)(b * 16 + h)) * 1024 + t) * 64 + f;
          if (zi == 0) {
            qf[idx] = acc[tm][tn][r];
          } else {
            ushort hu, mu, lu;
            split3(acc[tm][tn][r], hu, mu, lu);
            kh[idx] = hu; km[idx] = mu; kl[idx] = lu;
          }
        }
      }
    }
  } else {
    const ushort* wt = wT + (size_t)6 * (1u << 20);
    const ushort* bpb = wt + (size_t)(n0 + sr) * 1024 + q0 * 8;
    bf16x8 pb0 = *(const bf16x8*)(bpb);
    bf16x8 pb1 = *(const bf16x8*)(bpb + 8);
    for (int k0 = 0; k0 < 1024; k0 += 32) {
      __syncthreads();
      {
        float xs[16];
        *(float4*)&xs[0]  = px0;
        *(float4*)&xs[4]  = px1;
        *(float4*)&xs[8]  = px2;
        *(float4*)&xs[12] = px3;
        bf16x8 h0, h1;
#pragma unroll
        for (int j = 0; j < 8; ++j) {
          h0[j] = (short)f2bf(xs[j]);
          h1[j] = (short)f2bf(xs[j + 8]);
        }
        *(bf16x8*)&As[wb0] = h0; *(bf16x8*)&As[wb1] = h1;
        *(bf16x8*)&Bs[wb0] = pb0; *(bf16x8*)&Bs[wb1] = pb1;
      }
      __syncthreads();
      if (k0 < 992) {
        const float* nx = apx + k0 + 32;
        px0 = *(const float4*)(nx);
        px1 = *(const float4*)(nx + 4);
        px2 = *(const float4*)(nx + 8);
        px3 = *(const float4*)(nx + 12);
        pb0 = *(const bf16x8*)(bpb + k0 + 32);
        pb1 = *(const bf16x8*)(bpb + k0 + 40);
      }
      bf16x8 af[4];
#pragma unroll
      for (int tm = 0; tm < 4; ++tm)
        af[tm] = *(const bf16x8*)&As[FRAG_IDX(wm * 4 + tm, quad, l15)];
#pragma unroll
      for (int tn = 0; tn < 4; ++tn) {
        bf16x8 b0 = *(const bf16x8*)&Bs[FRAG_IDX(wn * 4 + tn, quad, l15)];
#pragma unroll
        for (int tm = 0; tm < 4; ++tm)
          acc[tm][tn] = __builtin_amdgcn_mfma_f32_16x16x32_bf16(af[tm], b0, acc[tm][tn], 0, 0, 0);
      }
    }
#pragma unroll
    for (int tm = 0; tm < 4; ++tm) {
#pragma unroll
      for (int tn = 0; tn < 4; ++tn) {
#pragma unroll
        for (int r = 0; r < 4; ++r) {
          int m = m0 + wm * 64 + tm * 16 + quad * 4 + r;
          int n = n0 + wn * 64 + tn * 16 + l15;
          int b = m >> 10, t = m & 1023, h = n >> 6, f = n & 63;
          vt[(((size_t)(b * 16 + h)) * 64 + f) * 1024 + t] = f2bf(acc[tm][tn][r]);
        }
      }
    }
  }
}

// ---------------------------------------------------------------------------
// Flash attention. Round 8: K/V staging fragments held in registers and
// refilled for the NEXT window during the compute phase (drain lands on the
// next iteration's barrier1, hidden under QK^T/softmax/PV) — same proven
// mechanism as proj rounds 3/5.
// ---------------------------------------------------------------------------
__global__ __launch_bounds__(512) void attn_mfma(
    const float* __restrict__ qf, const ushort* __restrict__ kh,
    const ushort* __restrict__ km, const ushort* __restrict__ kl,
    const ushort* __restrict__ vt, ushort* __restrict__ zh, ushort* __restrict__ zl)
{
  __shared__ ushort Ks[3][64][68];
  __shared__ ushort Vs[64][68];
  __shared__ ushort Pl[8][16][68];

  const int tid = threadIdx.x;
  const int wave = tid >> 6, lane = tid & 63;
  const int l15 = lane & 15, quad = lane >> 4;
  const int bh = blockIdx.y;
  const int qbase = blockIdx.x * 128;

  bf16x8 aqh[2], aqm[2], aql[2];
  {
    const int qrow = qbase + wave * 16 + l15;
    const float* qp = qf + ((size_t)bh * Tc + qrow) * Fc;
#pragma unroll
    for (int ks = 0; ks < 2; ++ks) {
      int f0 = ks * 32 + quad * 8;
      float4 x0 = *(const float4*)(qp + f0);
      float4 x1 = *(const float4*)(qp + f0 + 4);
      float xs[8] = {x0.x, x0.y, x0.z, x0.w, x1.x, x1.y, x1.z, x1.w};
#pragma unroll
      for (int j = 0; j < 8; ++j) {
        ushort hu, mu, lu;
        split3(xs[j], hu, mu, lu);
        aqh[ks][j] = (short)hu; aqm[ks][j] = (short)mu; aql[ks][j] = (short)lu;
      }
    }
  }

  f32x4 o[4] = {{0,0,0,0},{0,0,0,0},{0,0,0,0},{0,0,0,0}};
  float m_run[4], l_run[4];
#pragma unroll
  for (int r = 0; r < 4; ++r) { m_run[r] = -1e30f; l_run[r] = 0.f; }

  const int srow = tid >> 3, sc8 = tid & 7;
  const size_t kbase = (size_t)bh * Tc * Fc;
  const size_t vbase = (size_t)bh * Fc * Tc;
  const ushort* kp0 = kh + kbase + (size_t)srow * Fc + sc8 * 8;
  const ushort* kp1 = km + kbase + (size_t)srow * Fc + sc8 * 8;
  const ushort* kp2 = kl + kbase + (size_t)srow * Fc + sc8 * 8;
  const ushort* vp  = vt + vbase + (size_t)srow * Tc + sc8 * 8;

  // current-window staging fragments in registers
  bf16x8 pk0 = *(const bf16x8*)(kp0);
  bf16x8 pk1 = *(const bf16x8*)(kp1);
  bf16x8 pk2 = *(const bf16x8*)(kp2);
  bf16x8 pv  = *(const bf16x8*)(vp);

  for (int kt = 0; kt < Tc; kt += 64) {
    __syncthreads();
    {
      *(bf16x8*)&Ks[0][srow][sc8 * 8] = pk0;
      *(bf16x8*)&Ks[1][srow][sc8 * 8] = pk1;
      *(bf16x8*)&Ks[2][srow][sc8 * 8] = pk2;
      *(bf16x8*)&Vs[srow][sc8 * 8]    = pv;
    }
    __syncthreads();
    // Prefetch next window's K/V here (hidden under the compute below).
    if (kt < Tc - 64) {
      const size_t ko = (size_t)(kt + 64) * Fc;
      pk0 = *(const bf16x8*)(kp0 + ko);
      pk1 = *(const bf16x8*)(kp1 + ko);
      pk2 = *(const bf16x8*)(kp2 + ko);
      pv  = *(const bf16x8*)(vp + kt + 64);
    }

    f32x4 sacc[4] = {{0,0,0,0},{0,0,0,0},{0,0,0,0},{0,0,0,0}};
#pragma unroll
    for (int nt = 0; nt < 4; ++nt) {
      int key = nt * 16 + l15;
#pragma unroll
      for (int ks = 0; ks < 2; ++ks) {
        int f0 = ks * 32 + quad * 8;
        bf16x8 bh_ = *(const bf16x8*)&Ks[0][key][f0];
        bf16x8 bm_ = *(const bf16x8*)&Ks[1][key][f0];
        bf16x8 bl_ = *(const bf16x8*)&Ks[2][key][f0];
        sacc[nt] = __builtin_amdgcn_mfma_f32_16x16x32_bf16(aqh[ks], bh_, sacc[nt], 0, 0, 0);
        sacc[nt] = __builtin_amdgcn_mfma_f32_16x16x32_bf16(aqh[ks], bm_, sacc[nt], 0, 0, 0);
        sacc[nt] = __builtin_amdgcn_mfma_f32_16x16x32_bf16(aqm[ks], bh_, sacc[nt], 0, 0, 0);
        sacc[nt] = __builtin_amdgcn_mfma_f32_16x16x32_bf16(aqh[ks], bl_, sacc[nt], 0, 0, 0);
        sacc[nt] = __builtin_amdgcn_mfma_f32_16x16x32_bf16(aqm[ks], bm_, sacc[nt], 0, 0, 0);
        sacc[nt] = __builtin_amdgcn_mfma_f32_16x16x32_bf16(aql[ks], bh_, sacc[nt], 0, 0, 0);
      }
    }

    const int rowg0 = qbase + wave * 16 + quad * 4;
    float mx[4];
#pragma unroll
    for (int r = 0; r < 4; ++r) mx[r] = -1e30f;
#pragma unroll
    for (int nt = 0; nt < 4; ++nt) {
      int key = kt + nt * 16 + l15;
#pragma unroll
      for (int r = 0; r < 4; ++r) {
        float s = sacc[nt][r];
        if (key > rowg0 + r) s *= -1.0e9f + 1.0f;
        s *= 0.125f;
        sacc[nt][r] = s;
        mx[r] = fmaxf(mx[r], s);
      }
    }
#pragma unroll
    for (int r = 0; r < 4; ++r)
#pragma unroll
      for (int d = 1; d < 16; d <<= 1) mx[r] = fmaxf(mx[r], __shfl_xor(mx[r], d));

    float corr[4], ps[4];
#pragma unroll
    for (int r = 0; r < 4; ++r) {
      float m2 = fmaxf(m_run[r], mx[r]);
      corr[r] = __expf(m_run[r] - m2);
      m_run[r] = m2;
      ps[r] = 0.f;
    }
#pragma unroll
    for (int nt = 0; nt < 4; ++nt) {
#pragma unroll
      for (int r = 0; r < 4; ++r) {
        float p = __expf(sacc[nt][r] - m_run[r]);
        ps[r] += p;
        Pl[wave][quad * 4 + r][nt * 16 + l15] = f2bf(p);
      }
    }
#pragma unroll
    for (int r = 0; r < 4; ++r) {
#pragma unroll
      for (int d = 1; d < 16; d <<= 1) ps[r] += __shfl_xor(ps[r], d);
      l_run[r] = l_run[r] * corr[r] + ps[r];
#pragma unroll
      for (int ft = 0; ft < 4; ++ft) o[ft][r] *= corr[r];
    }

#pragma unroll
    for (int ks2 = 0; ks2 < 2; ++ks2) {
      bf16x8 pa = *(const bf16x8*)&Pl[wave][l15][ks2 * 32 + quad * 8];
#pragma unroll
      for (int ft = 0; ft < 4; ++ft) {
        bf16x8 vb = *(const bf16x8*)&Vs[ft * 16 + l15][ks2 * 32 + quad * 8];
        o[ft] = __builtin_amdgcn_mfma_f32_16x16x32_bf16(pa, vb, o[ft], 0, 0, 0);
      }
    }
  }

  const int b = bh >> 4, h = bh & 15;
#pragma unroll
  for (int r = 0; r < 4; ++r) {
    float inv = 1.f / l_run[r];
    int row = qbase + wave * 16 + quad * 4 + r;
    size_t base = ((size_t)(b * Tc + row)) * Ec + h * Fc;
#pragma unroll
    for (int ft = 0; ft < 4; ++ft) {
      ushort hu, lu;
      split2(o[ft][r] * inv, hu, lu);
      zh[base + ft * 16 + l15] = hu;
      zl[base + ft * 16 + l15] = lu;
    }
  }
}

// ---------------------------------------------------------------------------
// fr GEMM: tile 128x64 (round-5 proven: sr/q0 staging + reg-prefetch).
// ---------------------------------------------------------------------------
__global__ __launch_bounds__(256) void gemm_fr_mfma(
    const ushort* __restrict__ zh, const ushort* __restrict__ zl,
    const ushort* __restrict__ frT, const float* __restrict__ x,
    float* __restrict__ s1, float2* __restrict__ part)
{
  const int bb = blockIdx.z;
  const int m0 = blockIdx.x * 128, n0 = blockIdx.y * 64;
  __shared__ ushort Ah[4096], Al[4096], Bh[2048], Bl[2048];
  __shared__ float2 red[256];
  const int tid = threadIdx.x;
  const int wave = tid >> 6, lane = tid & 63, l15 = lane & 15, quad = lane >> 4;
  const int wm = wave >> 1, wn = wave & 1;
  const int sr = tid >> 1, q0 = (tid & 1) * 2;
  const int wb0 = FRAG_IDX(sr >> 4, q0, sr & 15);
  const int wb1 = FRAG_IDX(sr >> 4, q0 + 1, sr & 15);
  const int sr2 = tid >> 2, qb = tid & 3;
  const int wbB = FRAG_IDX(sr2 >> 4, qb, sr2 & 15);
  f32x4 acc[4][2] = {};
  const size_t abase = ((size_t)bb * 1024 + m0 + sr) * 1024 + q0 * 8;
  const size_t bbase = ((size_t)bb * 1024 + n0 + sr2) * 1024 + qb * 8;
  const ushort* blp = frT + (4u << 20);
  bf16x8 pAh0 = *(const bf16x8*)(zh + abase);
  bf16x8 pAh1 = *(const bf16x8*)(zh + abase + 8);
  bf16x8 pAl0 = *(const bf16x8*)(zl + abase);
  bf16x8 pAl1 = *(const bf16x8*)(zl + abase + 8);
  bf16x8 pBh  = *(const bf16x8*)(frT + bbase);
  bf16x8 pBl  = *(const bf16x8*)(blp + bbase);
  for (int k0 = 0; k0 < 1024; k0 += 32) {
    __syncthreads();
    {
      *(bf16x8*)&Ah[wb0] = pAh0;
      *(bf16x8*)&Ah[wb1] = pAh1;
      *(bf16x8*)&Al[wb0] = pAl0;
      *(bf16x8*)&Al[wb1] = pAl1;
      *(bf16x8*)&Bh[wbB] = pBh;
      *(bf16x8*)&Bl[wbB] = pBl;
    }
    __syncthreads();
    if (k0 < 992) {
      pAh0 = *(const bf16x8*)(zh + abase + k0 + 32);
      pAh1 = *(const bf16x8*)(zh + abase + k0 + 40);
      pAl0 = *(const bf16x8*)(zl + abase + k0 + 32);
      pAl1 = *(const bf16x8*)(zl + abase + k0 + 40);
      pBh  = *(const bf16x8*)(frT + bbase + k0 + 32);
      pBl  = *(const bf16x8*)(blp + bbase + k0 + 32);
    }
    bf16x8 ah[4], al[4];
#pragma unroll
    for (int tm = 0; tm < 4; ++tm) {
      ah[tm] = *(const bf16x8*)&Ah[FRAG_IDX(wm * 4 + tm, quad, l15)];
      al[tm] = *(const bf16x8*)&Al[FRAG_IDX(wm * 4 + tm, quad, l15)];
    }
#pragma unroll
    for (int tn = 0; tn < 2; ++tn) {
      const int bi = FRAG_IDX(wn * 2 + tn, quad, l15);
      bf16x8 b0 = *(const bf16x8*)&Bh[bi];
      bf16x8 b1 = *(const bf16x8*)&Bl[bi];
#pragma unroll
      for (int tm = 0; tm < 4; ++tm) {
        f32x4 a = acc[tm][tn];
        a = __builtin_amdgcn_mfma_f32_16x16x32_bf16(ah[tm], b0, a, 0, 0, 0);
        a = __builtin_amdgcn_mfma_f32_16x16x32_bf16(ah[tm], b1, a, 0, 0, 0);
        a = __builtin_amdgcn_mfma_f32_16x16x32_bf16(al[tm], b0, a, 0, 0, 0);
        acc[tm][tn] = a;
      }
    }
  }
  float sum = 0.f, sq = 0.f;
#pragma unroll
  for (int tm = 0; tm < 4; ++tm) {
#pragma unroll
    for (int tn = 0; tn < 2; ++tn) {
#pragma unroll
      for (int r = 0; r < 4; ++r) {
        int m = m0 + wm * 64 + tm * 16 + quad * 4 + r;
        int n = n0 + wn * 32 + tn * 16 + l15;
        size_t idx = ((size_t)bb * 1024 + m) * 1024 + n;
        float o = x[idx] + acc[tm][tn][r];
        s1[idx] = o;
        sum += o; sq += o * o;
      }
    }
  }
  red[tid] = make_float2(sum, sq);
  __syncthreads();
  for (int s = 128; s > 0; s >>= 1) {
    if (tid < s) { red[tid].x += red[tid + s].x; red[tid].y += red[tid + s].y; }
    __syncthreads();
  }
  if (tid == 0) part[bb * 128 + blockIdx.x * 16 + blockIdx.y] = red[0];
}

// ---------------------------------------------------------------------------
// ff GEMM: tile 128x64 (round-5 proven staging).
// ---------------------------------------------------------------------------
__global__ __launch_bounds__(256) void gemm_ff_mfma(
    const ushort* __restrict__ z1h, const ushort* __restrict__ z1l,
    const ushort* __restrict__ fwh, const ushort* __restrict__ fwl,
    const float* __restrict__ ffb, float* __restrict__ s2,
    float2* __restrict__ part)
{
  const int m0 = blockIdx.x * 128, n0 = blockIdx.y * 64;
  __shared__ ushort Ah[4096], Al[4096], Bh[2048], Bl[2048];
  __shared__ float2 red[256];
  const int tid = threadIdx.x;
  const int wave = tid >> 6, lane = tid & 63, l15 = lane & 15, quad = lane >> 4;
  const int wm = wave >> 1, wn = wave & 1;
  const int sr = tid >> 1, q0 = (tid & 1) * 2;
  const int wb0 = FRAG_IDX(sr >> 4, q0, sr & 15);
  const int wb1 = FRAG_IDX(sr >> 4, q0 + 1, sr & 15);
  const int sr2 = tid >> 2, qb = tid & 3;
  const int wbB = FRAG_IDX(sr2 >> 4, qb, sr2 & 15);
  f32x4 acc[4][2] = {};
  const size_t abase = (size_t)(m0 + sr) * 1024 + q0 * 8;
  const size_t bbase = (size_t)(n0 + sr2) * 1024 + qb * 8;
  bf16x8 pAh0 = *(const bf16x8*)(z1h + abase);
  bf16x8 pAh1 = *(const bf16x8*)(z1h + abase + 8);
  bf16x8 pAl0 = *(const bf16x8*)(z1l + abase);
  bf16x8 pAl1 = *(const bf16x8*)(z1l + abase + 8);
  bf16x8 pBh  = *(const bf16x8*)(fwh + bbase);
  bf16x8 pBl  = *(const bf16x8*)(fwl + bbase);
  for (int k0 = 0; k0 < 1024; k0 += 32) {
    __syncthreads();
    {
      *(bf16x8*)&Ah[wb0] = pAh0;
      *(bf16x8*)&Ah[wb1] = pAh1;
      *(bf16x8*)&Al[wb0] = pAl0;
      *(bf16x8*)&Al[wb1] = pAl1;
      *(bf16x8*)&Bh[wbB] = pBh;
      *(bf16x8*)&Bl[wbB] = pBl;
    }
    __syncthreads();
    if (k0 < 992) {
      pAh0 = *(const bf16x8*)(z1h + abase + k0 + 32);
      pAh1 = *(const bf16x8*)(z1h + abase + k0 + 40);
      pAl0 = *(const bf16x8*)(z1l + abase + k0 + 32);
      pAl1 = *(const bf16x8*)(z1l + abase + k0 + 40);
      pBh  = *(const bf16x8*)(fwh + bbase + k0 + 32);
      pBl  = *(const bf16x8*)(fwl + bbase + k0 + 32);
    }
    bf16x8 ah[4], al[4];
#pragma unroll
    for (int tm = 0; tm < 4; ++tm) {
      ah[tm] = *(const bf16x8*)&Ah[FRAG_IDX(wm * 4 + tm, quad, l15)];
      al[tm] = *(const bf16x8*)&Al[FRAG_IDX(wm * 4 + tm, quad, l15)];
    }
#pragma unroll
    for (int tn = 0; tn < 2; ++tn) {
      const int bi = FRAG_IDX(wn * 2 + tn, quad, l15);
      bf16x8 b0 = *(const bf16x8*)&Bh[bi];
      bf16x8 b1 = *(const bf16x8*)&Bl[bi];
#pragma unroll
      for (int tm = 0; tm < 4; ++tm) {
        f32x4 a = acc[tm][tn];
        a = __builtin_amdgcn_mfma_f32_16x16x32_bf16(ah[tm], b0, a, 0, 0, 0);
        a = __builtin_amdgcn_mfma_f32_16x16x32_bf16(ah[tm], b1, a, 0, 0, 0);
        a = __builtin_amdgcn_mfma_f32_16x16x32_bf16(al[tm], b0, a, 0, 0, 0);
        acc[tm][tn] = a;
      }
    }
  }
  float sum = 0.f, sq = 0.f;
#pragma unroll
  for (int tm = 0; tm < 4; ++tm) {
#pragma unroll
    for (int tn = 0; tn < 2; ++tn) {
#pragma unroll
      for (int r = 0; r < 4; ++r) {
        int m = m0 + wm * 64 + tm * 16 + quad * 4 + r;
        int n = n0 + wn * 32 + tn * 16 + l15;
        size_t idx = (size_t)m * 1024 + n;
        float z1v = bf2f(z1h[idx]) + bf2f(z1l[idx]);
        float o = z1v + fmaxf(acc[tm][tn][r] + ffb[n], 0.f);
        s2[idx] = o;
        sum += o; sq += o * o;
      }
    }
  }
  red[tid] = make_float2(sum, sq);
  __syncthreads();
  for (int s = 128; s > 0; s >>= 1) {
    if (tid < s) { red[tid].x += red[tid + s].x; red[tid].y += red[tid + s].y; }
    __syncthreads();
  }
  if (tid == 0) part[blockIdx.x * 16 + blockIdx.y] = red[0];
}

// ---------------------------------------------------------------------------
// LN stats from partials, computed in-block (wave 0) — replaces the separate
// ln_stats dispatch. Double accumulation, order-insensitive at tolerance.
// ---------------------------------------------------------------------------
__device__ __forceinline__ float2 ln_stats_inblock(
    const float2* __restrict__ part, int b, int tid, float2* st_sh)
{
  if (tid < 64) {
    float2 p0 = part[b * 128 + tid * 2];
    float2 p1 = part[b * 128 + tid * 2 + 1];
    double as = (double)p0.x + (double)p1.x;
    double aq = (double)p0.y + (double)p1.y;
#pragma unroll
    for (int d = 1; d < 64; d <<= 1) {
      as += __shfl_xor(as, d);
      aq += __shfl_xor(aq, d);
    }
    if (tid == 0) {
      const double n = (double)Tc * Ec;
      double mean = as / n;
      double var = aq / n - mean * mean;
      if (var < 0.0) var = 0.0;
      *st_sh = make_float2((float)mean, (float)(1.0 / sqrt(var + 1e-5)));
    }
  }
  __syncthreads();
  return *st_sh;
}

// ln_norm -> split2 pair; blocks >= 4096 instead split2 ffw (folded launch).
__global__ __launch_bounds__(256) void ln_norm_split(
    const float* __restrict__ s, const float2* __restrict__ part,
    const float* __restrict__ w, const float* __restrict__ bias,
    ushort* __restrict__ oh, ushort* __restrict__ ol,
    const float* __restrict__ ffw, ushort* __restrict__ fwh, ushort* __restrict__ fwl)
{
  if (blockIdx.x >= 4096) {
    int i = (blockIdx.x - 4096) * 256 + threadIdx.x;
#pragma unroll
    for (int j = 0; j < 4; ++j) {
      int idx = i * 4 + j;
      float4 v = ((const float4*)ffw)[idx];
      ushort4 h, l;
      split2(v.x, h.x, l.x); split2(v.y, h.y, l.y);
      split2(v.z, h.z, l.z); split2(v.w, h.w, l.w);
      ((ushort4*)fwh)[idx] = h; ((ushort4*)fwl)[idx] = l;
    }
    return;
  }
  __shared__ float2 st_sh;
  const int tid = threadIdx.x;
  int i = blockIdx.x * 256 + tid;
  int b = i >> 18;  // uniform per block (1024 blocks per batch)
  float2 st = ln_stats_inblock(part, b, tid, &st_sh);
  int te4 = i & ((1 << 18) - 1);
  float4 sv = ((const float4*)s)[i];
  float4 wv = ((const float4*)w)[te4];
  float4 bv = ((const float4*)bias)[te4];
  float4 o;
  o.x = (sv.x - st.x) * st.y * wv.x + bv.x;
  o.y = (sv.y - st.x) * st.y * wv.y + bv.y;
  o.z = (sv.z - st.x) * st.y * wv.z + bv.z;
  o.w = (sv.w - st.x) * st.y * wv.w + bv.w;
  ushort4 h, l;
  split2(o.x, h.x, l.x); split2(o.y, h.y, l.y);
  split2(o.z, h.z, l.z); split2(o.w, h.w, l.w);
  ((ushort4*)oh)[i] = h; ((ushort4*)ol)[i] = l;
}

__global__ __launch_bounds__(256) void ln_norm(
    const float* __restrict__ s, const float2* __restrict__ part,
    const float* __restrict__ w, const float* __restrict__ bias,
    float* __restrict__ out)
{
  __shared__ float2 st_sh;
  const int tid = threadIdx.x;
  int i = blockIdx.x * 256 + tid;
  int b = i >> 18;
  float2 st = ln_stats_inblock(part, b, tid, &st_sh);
  int te4 = i & ((1 << 18) - 1);
  float4 sv = ((const float4*)s)[i];
  float4 wv = ((const float4*)w)[te4];
  float4 bv = ((const float4*)bias)[te4];
  float4 o;
  o.x = (sv.x - st.x) * st.y * wv.x + bv.x;
  o.y = (sv.y - st.x) * st.y * wv.y + bv.y;
  o.z = (sv.z - st.x) * st.y * wv.z + bv.z;
  o.w = (sv.w - st.x) * st.y * wv.w + bv.w;
  ((float4*)out)[i] = o;
}

// ---------------------------------------------------------------------------
extern "C" void kernel_launch(void* const* d_in, const int* in_sizes, int n_in,
                              void* d_out, int out_size, void* d_ws, size_t ws_size,
                              hipStream_t stream)
{
  const float* x    = (const float*)d_in[0];
  const float* qw   = (const float*)d_in[1];
  const float* kw   = (const float*)d_in[2];
  const float* vw   = (const float*)d_in[3];
  const float* frw  = (const float*)d_in[4];
  const float* ffw  = (const float*)d_in[5];
  const float* ffb  = (const float*)d_in[6];
  const float* ln1w = (const float*)d_in[7];
  const float* ln1b = (const float*)d_in[8];
  const float* ln2w = (const float*)d_in[9];
  const float* ln2b = (const float*)d_in[10];
  float* out = (float*)d_out;
  char* W = (char*)d_ws;

  const size_t MB = 1ull << 20;
  float*  qf  = (float*)(W);
  ushort* kh  = (ushort*)(W + 16 * MB);
  ushort* km  = (ushort*)(W + 24 * MB);
  ushort* kl  = (ushort*)(W + 32 * MB);
  ushort* vt  = (ushort*)(W + 40 * MB);
  ushort* wT  = (ushort*)(W + 48 * MB);
  ushort* zh  = (ushort*)(W + 48 * MB);
  ushort* zl  = (ushort*)(W + 56 * MB);
  ushort* frT = (ushort*)(W + 16 * MB);
  float*  s1  = (float*)(W);
  ushort* z1h = (ushort*)(W + 16 * MB);
  ushort* z1l = (ushort*)(W + 24 * MB);
  ushort* fwh = (ushort*)(W + 48 * MB);
  ushort* fwl = (ushort*)(W + 50 * MB);
  float*  s2  = (float*)(W + 32 * MB);
  float2* part1  = (float2*)(W + 64 * MB);
  float2* part2  = part1 + 1024;
  // x pre-split planes (only used when workspace permits)
  ushort* xh = (ushort*)(W + 65 * MB);
  ushort* xm = (ushort*)(W + 73 * MB);
  ushort* xl = (ushort*)(W + 81 * MB);
  const bool big_ws = ws_size >= 90 * MB;

  if (big_ws) {
    // z<3: weight transpose+split; z>=3: x_split (8 z-slices x 256 blocks)
    prep_all<<<dim3(16, 16, 11), 256, 0, stream>>>(qw, kw, vw, wT, x, xh, xm, xl);
    proj_all_ps<<<dim3(32, 8, 3), 256, 0, stream>>>(xh, xm, xl, wT, qf, kh, km, kl, vt);
  } else {
    prep_all<<<dim3(16, 16, 3), 256, 0, stream>>>(qw, kw, vw, wT, x, xh, xm, xl);
    proj_all_mfma<<<dim3(32, 8, 3), 256, 0, stream>>>(x, wT, qf, kh, km, kl, vt);
  }
  attn_mfma<<<dim3(8, 64), 512, 0, stream>>>(qf, kh, km, kl, vt, zh, zl);
  transp_frw<<<dim3(16, 16, 4), 256, 0, stream>>>(frw, frT);
  gemm_fr_mfma<<<dim3(8, 16, 4), 256, 0, stream>>>(zh, zl, frT, x, s1, part1);
  ln_norm_split<<<dim3(4352), 256, 0, stream>>>(s1, part1, ln1w, ln1b, z1h, z1l,
                                                ffw, fwh, fwl);
  gemm_ff_mfma<<<dim3(32, 16), 256, 0, stream>>>(z1h, z1l, fwh, fwl, ffb, s2, part2);
  ln_norm<<<dim3(4096), 256, 0, stream>>>(s2, part2, ln2w, ln2b, out);
}